// Round 1
// baseline (361.350 us; speedup 1.0000x reference)
//
#include <hip/hip_runtime.h>

#define Bn 2
#define Ln 2048
#define DIN 256
#define Hn 8
#define DEPTH 32
#define SCALE 0.17677669529663687f      // 1/sqrt(32)
#define NEGC (-4294967296.0f)           // float32(-2^32+1)
#define NG  (Ln / 16)                   // 128 16-row groups per (b,h)
#define WLS 264                         // LDS W^T row stride (f16)
#define NBLK 512                        // grid of the fused kernel

typedef _Float16 f16;
typedef _Float16 h8 __attribute__((ext_vector_type(8)));   // K=32 A/B frag: 4 VGPR
typedef _Float16 h4 __attribute__((ext_vector_type(4)));   // K=16 A/B frag: 2 VGPR
typedef float f4 __attribute__((ext_vector_type(4)));      // C/D frag: 4 f32

// ===========================================================================
// ZERO-WORKSPACE layout inside d_out (4096 row slots x 1 KB):
//   slot r = bytes [r*1024, r*1024+1024) = out16[r*512 .. r*512+512)
//   phase P (proj_kv):  Kz flat[0,1M) -> out16[(i>>8)*512 + 256 + (i&255)]
//                        (second halves), Vz flat -> out16[(i>>8)*512 + (i&255)]
//                        (first halves).  K chunk C (512 f16) = slots 2C,2C+1.
//   phase F (flash):    reads both; O kept in regs across grid barrier; then
//                        Oz row r feature c -> out16[r*512 + c]  (over dead V)
//   phase O (out-proj): block owns rows [16b,16b+16) exclusively: reads its
//                        own Oz -> regs, then overwrites with final f32 rows.
// Device-scope grid barrier: monotonic counter (no reset needed -> safe under
// hipGraph replay and rocprof counter replay).
// ===========================================================================

__device__ int g_bar = 0;

__device__ __forceinline__ void grid_bar() {
    __threadfence();                         // release: flush my writes device-wide
    __syncthreads();
    if (threadIdx.x == 0) {
        int tk = __hip_atomic_fetch_add(&g_bar, 1, __ATOMIC_ACQ_REL,
                                        __HIP_MEMORY_SCOPE_AGENT) + 1;
        int target = ((tk + NBLK - 1) / NBLK) * NBLK;   // ceil to multiple of NBLK
        while (__hip_atomic_load(&g_bar, __ATOMIC_ACQUIRE,
                                 __HIP_MEMORY_SCOPE_AGENT) < target)
            __builtin_amdgcn_s_sleep(8);
    }
    __syncthreads();
    __threadfence();                         // acquire: invalidate stale L1 lines
}

// ---- Kernel 1: K/V projection GEMM into out-slot halves. ------------------
__global__ __launch_bounds__(256) void proj_kv(
    const float* __restrict__ Xk, const float* __restrict__ Xv,
    const float* __restrict__ Wk, const float* __restrict__ Wv,
    const float* __restrict__ bk, const float* __restrict__ bv,
    f16* __restrict__ S)                     // = (f16*)d_out
{
    __shared__ f16 Wl[64 * WLS];             // 33.8 KB: W^T tile [n_local][k]
    const int p = blockIdx.z;                // 0 -> K, 1 -> V
    const float* X = p ? Xv : Xk;
    const float* W = p ? Wv : Wk;
    const float* bias = p ? bv : bk;

    const int t = threadIdx.x, w = t >> 6, lane = t & 63;
    const int l15 = lane & 15, quad = lane >> 4;
    const int n0 = blockIdx.y * 64;

    {   // stage W[k][n0+nl] -> Wl[nl][k] (f16); coalesced 256B global rows
        const int nl = t & 63, kb = t >> 6;
        for (int kk = 0; kk < 64; ++kk) {
            const int k = kk * 4 + kb;
            Wl[nl * WLS + k] = (f16)W[(size_t)k * DIN + n0 + nl];
        }
    }
    __syncthreads();

    const int m0w = blockIdx.x * 128 + w * 32;
    const float* A0 = X + (size_t)(m0w + l15) * DIN;
    const float* A1 = X + (size_t)(m0w + 16 + l15) * DIN;

    f4 acc[2][4];
    #pragma unroll
    for (int mi = 0; mi < 2; ++mi)
        #pragma unroll
        for (int tt = 0; tt < 4; ++tt) acc[mi][tt] = (f4){0.f, 0.f, 0.f, 0.f};

    for (int k0 = 0; k0 < DIN; k0 += 32) {
        float4 xa0 = *(const float4*)(A0 + k0 + quad * 8);
        float4 xb0 = *(const float4*)(A0 + k0 + quad * 8 + 4);
        float4 xa1 = *(const float4*)(A1 + k0 + quad * 8);
        float4 xb1 = *(const float4*)(A1 + k0 + quad * 8 + 4);
        h8 af0 = { (f16)xa0.x, (f16)xa0.y, (f16)xa0.z, (f16)xa0.w,
                   (f16)xb0.x, (f16)xb0.y, (f16)xb0.z, (f16)xb0.w };
        h8 af1 = { (f16)xa1.x, (f16)xa1.y, (f16)xa1.z, (f16)xa1.w,
                   (f16)xb1.x, (f16)xb1.y, (f16)xb1.z, (f16)xb1.w };
        #pragma unroll
        for (int tt = 0; tt < 4; ++tt) {
            h8 bf = *(const h8*)(Wl + (tt * 16 + l15) * WLS + k0 + quad * 8);
            acc[0][tt] = __builtin_amdgcn_mfma_f32_16x16x32_f16(af0, bf, acc[0][tt], 0, 0, 0);
            acc[1][tt] = __builtin_amdgcn_mfma_f32_16x16x32_f16(af1, bf, acc[1][tt], 0, 0, 0);
        }
    }
    #pragma unroll
    for (int mi = 0; mi < 2; ++mi)
        #pragma unroll
        for (int tt = 0; tt < 4; ++tt) {
            const int c = n0 + tt * 16 + l15;     // 16-tile never straddles a head
            const float bb = bias[c];
            const int h = c >> 5, dd = c & 31;
            #pragma unroll
            for (int r = 0; r < 4; ++r) {
                const int row = m0w + mi * 16 + quad * 4 + r;
                const int b = row >> 11, l = row & (Ln - 1);
                const float v = acc[mi][tt][r] + bb;
                const size_t hbg = (size_t)(b * Hn + h) * NG + (l >> 4);
                if (!p) {   // K swizzled (K=32 A-frag chunks) -> second halves
                    const size_t i = (hbg * 64 + (size_t)(dd >> 3) * 16 + (l & 15)) * 8 + (dd & 7);
                    S[(i >> 8) * 512 + 256 + (i & 255)] = (f16)v;
                } else {    // V swizzled (K=16 A-frag chunks, 2 d-halves) -> first halves
                    const size_t i = ((hbg * 2 + (dd >> 4)) * 64 + (size_t)((l & 15) >> 2) * 16
                                      + (dd & 15)) * 4 + (l & 3);
                    S[(i >> 8) * 512 + (i & 255)] = (f16)v;
                }
            }
        }
}

// ---- Kernel 2: Q-proj + split-K MFMA flash + out-proj, 2 grid barriers. ---
__global__ __launch_bounds__(256, 2) void fused_attn_out(
    const float* __restrict__ Xq, const float* __restrict__ Wq,
    const float* __restrict__ bq, const int* __restrict__ mask,
    const float* __restrict__ Wo, const float* __restrict__ bo,
    float* out)                               // aliases all scratch - no restrict
{
    __shared__ union {
        f16 Qs[4 * 512];                               // 4 KB  (phase 2a)
        struct { float Os[4][32][68]; float lS[4][64]; } c;  // 35.8 KB (flash combine)
    } sm;

    f16* S = (f16*)out;
    const int t = threadIdx.x, w = t >> 6, lane = t & 63;
    const int l15 = lane & 15, quad = lane >> 4;
    const int hb = blockIdx.x >> 5, qc = blockIdx.x & 31;
    const int b = hb >> 3, h = hb & 7, q0 = qc * 64;

    // ---- phase 2a: Q projection (64 rows x 32 cols, K=256), MFMA ----
    {
        const float* A0 = Xq + (size_t)(b * Ln + q0 + w * 16 + l15) * DIN;
        const float* Wp = Wq + h * 32 + l15;
        f4 a2[2] = { {0.f,0.f,0.f,0.f}, {0.f,0.f,0.f,0.f} };
        #pragma unroll
        for (int kk = 0; kk < 8; ++kk) {
            const int k0 = kk * 32;
            float4 xa = *(const float4*)(A0 + k0 + quad * 8);
            float4 xb = *(const float4*)(A0 + k0 + quad * 8 + 4);
            h8 af = { (f16)xa.x, (f16)xa.y, (f16)xa.z, (f16)xa.w,
                      (f16)xb.x, (f16)xb.y, (f16)xb.z, (f16)xb.w };
            #pragma unroll
            for (int tt = 0; tt < 2; ++tt) {
                h8 bf;
                #pragma unroll
                for (int j = 0; j < 8; ++j)
                    bf[j] = (f16)Wp[(size_t)(k0 + quad * 8 + j) * DIN + tt * 16];
                a2[tt] = __builtin_amdgcn_mfma_f32_16x16x32_f16(af, bf, a2[tt], 0, 0, 0);
            }
        }
        #pragma unroll
        for (int tt = 0; tt < 2; ++tt) {
            const int c = tt * 16 + l15;               // depth 0..31
            const float bb = bq[h * 32 + c];
            #pragma unroll
            for (int r = 0; r < 4; ++r) {
                const int lc = quad * 4 + r;           // row within 16-group
                sm.Qs[((size_t)w * 64 + (c >> 3) * 16 + lc) * 8 + (c & 7)] =
                    (f16)((a2[tt][r] + bb) * SCALE);
            }
        }
    }
    __syncthreads();
    h8 qf[4];
    #pragma unroll
    for (int qg = 0; qg < 4; ++qg)
        qf[qg] = *(const h8*)(sm.Qs + ((size_t)qg * 64 + lane) * 8);
    __syncthreads();   // Qs dead; union reused as Os/lS below

    // ---- phase 2b: split-K flash (wave w = keys [w*512,(w+1)*512)) ----
    const int* mrow = mask + b * Ln;
    const f16* Kb = S + (size_t)hb * NG * 1024 + 256 + (lane >> 5) * 512 + (lane & 31) * 8;
    const f16* Vb = S + (size_t)hb * NG * 1024 + lane * 4;

    f4 o[2][4];
    #pragma unroll
    for (int i = 0; i < 2; ++i)
        #pragma unroll
        for (int j = 0; j < 4; ++j) o[i][j] = (f4){0.f, 0.f, 0.f, 0.f};
    float l_run[4] = {0.f, 0.f, 0.f, 0.f};
    const int k_base = w * (Ln / 4);

    for (int kt = 0; kt < Ln / 4 / 64; ++kt) {
        const int k0 = k_base + kt * 64;
        #pragma unroll
        for (int tt = 0; tt < 4; ++tt) {
            const int g = (k0 >> 4) + tt;              // group within (b,h): 0..127
            h8 kf = *(const h8*)(Kb + (size_t)g * 1024);
            const int4 mk = *(const int4*)(mrow + g * 16 + quad * 4);
            f4 bias4 = { mk.x ? 0.f : NEGC, mk.y ? 0.f : NEGC,
                         mk.z ? 0.f : NEGC, mk.w ? 0.f : NEGC };
            h4 va0 = *(const h4*)(Vb + (size_t)g * 1024);
            h4 va1 = *(const h4*)(Vb + (size_t)g * 1024 + 512);
            f4 s_[4];
            #pragma unroll
            for (int qg = 0; qg < 4; ++qg)
                s_[qg] = __builtin_amdgcn_mfma_f32_16x16x32_f16(kf, qf[qg], bias4, 0, 0, 0);
            #pragma unroll
            for (int qg = 0; qg < 4; ++qg) {
                h4 pf;
                #pragma unroll
                for (int r = 0; r < 4; ++r) {
                    const float pv = __expf(s_[qg][r]);
                    l_run[qg] += pv;
                    pf[r] = (f16)pv;
                }
                o[0][qg] = __builtin_amdgcn_mfma_f32_16x16x16f16(va0, pf, o[0][qg], 0, 0, 0);
                o[1][qg] = __builtin_amdgcn_mfma_f32_16x16x16f16(va1, pf, o[1][qg], 0, 0, 0);
            }
        }
    }
    // ---- wave partials ----
    #pragma unroll
    for (int qg = 0; qg < 4; ++qg) {
        l_run[qg] += __shfl_xor(l_run[qg], 16, 64);
        l_run[qg] += __shfl_xor(l_run[qg], 32, 64);
        if (quad == 0) sm.c.lS[w][qg * 16 + l15] = l_run[qg];
        #pragma unroll
        for (int dg = 0; dg < 2; ++dg)
            #pragma unroll
            for (int r = 0; r < 4; ++r)
                sm.c.Os[w][dg * 16 + quad * 4 + r][qg * 16 + l15] = o[dg][qg][r];
    }
    __syncthreads();

    // ---- combine 4 split-K chunks -> Oz slice held in regs ----
    const int cq = t & 63, dv = t >> 6;
    const float ls = sm.c.lS[0][cq] + sm.c.lS[1][cq] + sm.c.lS[2][cq] + sm.c.lS[3][cq];
    const float inv = 1.0f / ls;
    h8 pack;
    #pragma unroll
    for (int i = 0; i < 8; ++i) {
        const int dd = dv * 8 + i;
        const float ov = sm.c.Os[0][dd][cq] + sm.c.Os[1][dd][cq] +
                         sm.c.Os[2][dd][cq] + sm.c.Os[3][dd][cq];
        pack[i] = (f16)(ov * inv);
    }

    grid_bar();     // all K/V reads complete chip-wide -> V region is dead

    // ---- phase 3: Oz row r, feature c -> out16[r*512 + c] (first halves) ----
    *(h8*)(S + (size_t)(b * Ln + q0 + cq) * 512 + h * 32 + dv * 8) = pack;

    grid_bar();     // all Oz writes complete chip-wide

    // ---- phase 4: out-proj; block owns rows [16*bx, 16*bx+16) exclusively ----
    if (blockIdx.x < 256) {
        const int m0 = blockIdx.x * 16;
        h8 af[8];
        #pragma unroll
        for (int kk = 0; kk < 8; ++kk)
            af[kk] = *(const h8*)(S + (size_t)(m0 + l15) * 512 + kk * 32 + quad * 8);
        __syncthreads();   // all waves hold their Oz rows before any f32 overwrite

        const float* Wop = Wo + w * 64 + l15;
        f4 a4[4];
        #pragma unroll
        for (int tt = 0; tt < 4; ++tt) a4[tt] = (f4){0.f, 0.f, 0.f, 0.f};
        #pragma unroll
        for (int tt = 0; tt < 4; ++tt)
            #pragma unroll
            for (int kk = 0; kk < 8; ++kk) {
                h8 bf;
                #pragma unroll
                for (int j = 0; j < 8; ++j)
                    bf[j] = (f16)Wop[(size_t)(kk * 32 + quad * 8 + j) * DIN + tt * 16];
                a4[tt] = __builtin_amdgcn_mfma_f32_16x16x32_f16(af[kk], bf, a4[tt], 0, 0, 0);
            }
        #pragma unroll
        for (int tt = 0; tt < 4; ++tt) {
            const int c = w * 64 + tt * 16 + l15;
            const float bb = bo[c];
            #pragma unroll
            for (int r = 0; r < 4; ++r)
                out[(size_t)(m0 + quad * 4 + r) * DIN + c] = a4[tt][r] + bb;
        }
    }
}

// ===========================================================================
extern "C" void kernel_launch(void* const* d_in, const int* in_sizes, int n_in,
                              void* d_out, int out_size, void* d_ws, size_t ws_size,
                              hipStream_t stream) {
    (void)in_sizes; (void)n_in; (void)d_ws; (void)ws_size; (void)out_size;
    const float* Xq = (const float*)d_in[0];
    const float* Xk = (const float*)d_in[1];
    const float* Xv = (const float*)d_in[2];
    const int*  mask = (const int*)d_in[3];
    const float* Wq = (const float*)d_in[4];
    const float* bq = (const float*)d_in[5];
    const float* Wk = (const float*)d_in[6];
    const float* bk = (const float*)d_in[7];
    const float* Wv = (const float*)d_in[8];
    const float* bv = (const float*)d_in[9];
    const float* Wo = (const float*)d_in[10];
    const float* bo = (const float*)d_in[11];
    float* out = (float*)d_out;

    // ZERO workspace: all intermediates live inside d_out (see layout note).
    proj_kv<<<dim3(Bn * Ln / 128, DIN / 64, 2), 256, 0, stream>>>(
        Xk, Xv, Wk, Wv, bk, bv, (f16*)out);
    fused_attn_out<<<dim3(NBLK), 256, 0, stream>>>(
        Xq, Wq, bq, mask, Wo, bo, out);
}

// Round 2
// 229.179 us; speedup vs baseline: 1.5767x; 1.5767x over previous
//
#include <hip/hip_runtime.h>

#define Bn 2
#define Ln 2048
#define DIN 256
#define Hn 8
#define DEPTH 32
#define SCALE 0.17677669529663687f      // 1/sqrt(32)
#define NEGC (-4294967296.0f)           // float32(-2^32+1)
#define WLS 264                         // LDS W^T row stride (f16)

// f16-element offsets inside d_out (4 MB = 2M f16):
//   [0,       524288)  Kz for current batch (8 heads x 128 groups x 512 f16)
//   [524288, 1048576)  Vz for current batch
//   [1048576,2097152)  Oz for BOTH batches: chunk (gm,h) at
//                      1048576 + ((gm*8+h)*64 + frag)*8,  gm = global row>>4
//                      => Oz of global row r occupies bytes 2M + r*512.
#define VZB 524288
#define OZB 1048576

typedef _Float16 f16;
typedef _Float16 h8 __attribute__((ext_vector_type(8)));   // K=32 A/B frag
typedef _Float16 h4 __attribute__((ext_vector_type(4)));   // K=16 A/B frag
typedef float f4 __attribute__((ext_vector_type(4)));      // C/D frag

// ===========================================================================
// Schedule (11 launches, sync + coherence from kernel boundaries only):
//  L1  projKV(b=0) -> KV at [0,2M)
//  L2  flashQ(b=0): reads [0,2M), writes Oz rows 0..2047    -> [2,3M)
//  L3  projKV(b=1) -> KV at [0,2M)        (K0V0 dead after L2)
//  L4  flashQ(b=1): reads [0,2M), writes Oz rows 2048..4095 -> [3,4M)
//  L5  outproj rows    0..2047: reads [2,3M),        writes [0,2M)
//  L6  outproj rows 2048..3071: reads [3,3.5M),      writes [2,3M)
//  L7  outproj rows 3072..3583: reads [3.5,3.75M),   writes [3,3.5M)
//  L8  outproj rows 3584..3839: reads [3.75,3.875M), writes [3.5,3.75M)
//  L9  outproj rows 3840..3967: reads [3.875,3.9375M), writes [3.75,3.875M)
//  L10 outproj rows 3968..4031: reads [3.9375,3.96875M), writes [3.875,3.9375M)
//  L11 out_tail rows 4032..4095 (1 block): Oz->regs, sync, overwrite own region
// Every launch's write region is dead (consumed by an earlier launch) and
// disjoint from every read region of the same launch.
// ===========================================================================

// ---- K/V projection GEMM for one batch into [0,2M). -----------------------
__global__ __launch_bounds__(256) void projKV(
    const float* __restrict__ Xk, const float* __restrict__ Xv,
    const float* __restrict__ Wk, const float* __restrict__ Wv,
    const float* __restrict__ bk, const float* __restrict__ bv,
    f16* __restrict__ S, int b)
{
    __shared__ f16 Wl[64 * WLS];             // 33.8 KB: W^T tile [n_local][k]
    const int p = blockIdx.z;                // 0 -> K, 1 -> V
    const float* X = (p ? Xv : Xk) + (size_t)b * Ln * DIN;
    const float* W = p ? Wv : Wk;
    const float* bias = p ? bv : bk;

    const int t = threadIdx.x, w = t >> 6, lane = t & 63;
    const int l15 = lane & 15, quad = lane >> 4;
    const int n0 = blockIdx.y * 64;

    {   // stage W[k][n0+nl] -> Wl[nl][k] (f16); coalesced 256B global rows
        const int nl = t & 63, kb = t >> 6;
        for (int kk = 0; kk < 64; ++kk) {
            const int k = kk * 4 + kb;
            Wl[nl * WLS + k] = (f16)W[(size_t)k * DIN + n0 + nl];
        }
    }
    __syncthreads();

    const int m0w = blockIdx.x * 128 + w * 32;
    const float* A0 = X + (size_t)(m0w + l15) * DIN;
    const float* A1 = X + (size_t)(m0w + 16 + l15) * DIN;

    f4 acc[2][4];
    #pragma unroll
    for (int mi = 0; mi < 2; ++mi)
        #pragma unroll
        for (int tt = 0; tt < 4; ++tt) acc[mi][tt] = (f4){0.f, 0.f, 0.f, 0.f};

    for (int k0 = 0; k0 < DIN; k0 += 32) {
        float4 xa0 = *(const float4*)(A0 + k0 + quad * 8);
        float4 xb0 = *(const float4*)(A0 + k0 + quad * 8 + 4);
        float4 xa1 = *(const float4*)(A1 + k0 + quad * 8);
        float4 xb1 = *(const float4*)(A1 + k0 + quad * 8 + 4);
        h8 af0 = { (f16)xa0.x, (f16)xa0.y, (f16)xa0.z, (f16)xa0.w,
                   (f16)xb0.x, (f16)xb0.y, (f16)xb0.z, (f16)xb0.w };
        h8 af1 = { (f16)xa1.x, (f16)xa1.y, (f16)xa1.z, (f16)xa1.w,
                   (f16)xb1.x, (f16)xb1.y, (f16)xb1.z, (f16)xb1.w };
        #pragma unroll
        for (int tt = 0; tt < 4; ++tt) {
            h8 bf = *(const h8*)(Wl + (tt * 16 + l15) * WLS + k0 + quad * 8);
            acc[0][tt] = __builtin_amdgcn_mfma_f32_16x16x32_f16(af0, bf, acc[0][tt], 0, 0, 0);
            acc[1][tt] = __builtin_amdgcn_mfma_f32_16x16x32_f16(af1, bf, acc[1][tt], 0, 0, 0);
        }
    }
    #pragma unroll
    for (int mi = 0; mi < 2; ++mi)
        #pragma unroll
        for (int tt = 0; tt < 4; ++tt) {
            const int c = n0 + tt * 16 + l15;     // 16-tile never straddles a head
            const float bb = bias[c];
            const int h = c >> 5, dd = c & 31;
            #pragma unroll
            for (int r = 0; r < 4; ++r) {
                const int l = m0w + mi * 16 + quad * 4 + r;   // 0..2047 in-batch
                const float v = acc[mi][tt][r] + bb;
                const size_t hg = (size_t)h * 128 + (l >> 4);
                if (!p)     // K swizzled (K=32 A-frag chunks)
                    S[(hg * 64 + (size_t)(dd >> 3) * 16 + (l & 15)) * 8 + (dd & 7)] = (f16)v;
                else        // V swizzled (K=16 A-frag chunks, 2 d-halves)
                    S[VZB + ((hg * 2 + (dd >> 4)) * 64 + (size_t)((l & 15) >> 2) * 16
                             + (dd & 15)) * 4 + (l & 3)] = (f16)v;
            }
        }
}

// ---- Q-proj (LDS-staged Wq) + split-K MFMA flash for one batch. -----------
__global__ __launch_bounds__(256) void flashQ(
    const float* __restrict__ Xq, const float* __restrict__ Wq,
    const float* __restrict__ bq, const int* __restrict__ mask,
    float* outbuf, int b)                     // aliases scratch - no restrict
{
    __shared__ union {
        struct { f16 Wlq[32 * WLS]; f16 Qs[2048]; } a;        // 21.0 KB
        struct { float Os[4][32][68]; float lS[4][64]; } c;   // 35.8 KB
    } sm;
    f16* S = (f16*)outbuf;
    const int t = threadIdx.x, w = t >> 6, lane = t & 63;
    const int l15 = lane & 15, quad = lane >> 4;
    const int h = blockIdx.x, q0 = blockIdx.y * 64;

    {   // stage Wq[:, h*32 + nl] -> Wlq[nl][k]; coalesced 128B row segments
        const int nl = t & 31, kb = t >> 5;
        for (int kk = 0; kk < 32; ++kk) {
            const int k = kk * 8 + kb;
            sm.a.Wlq[nl * WLS + k] = (f16)Wq[(size_t)k * DIN + h * 32 + nl];
        }
    }
    __syncthreads();

    {   // Q-proj: 64 rows x 32 cols, K=256, MFMA
        const float* A0 = Xq + (size_t)(b * Ln + q0 + w * 16 + l15) * DIN;
        f4 a2[2] = { {0.f,0.f,0.f,0.f}, {0.f,0.f,0.f,0.f} };
        #pragma unroll
        for (int kk = 0; kk < 8; ++kk) {
            const int k0 = kk * 32;
            float4 xa = *(const float4*)(A0 + k0 + quad * 8);
            float4 xb = *(const float4*)(A0 + k0 + quad * 8 + 4);
            h8 af = { (f16)xa.x, (f16)xa.y, (f16)xa.z, (f16)xa.w,
                      (f16)xb.x, (f16)xb.y, (f16)xb.z, (f16)xb.w };
            #pragma unroll
            for (int tt = 0; tt < 2; ++tt) {
                h8 bf = *(const h8*)(sm.a.Wlq + (tt * 16 + l15) * WLS + k0 + quad * 8);
                a2[tt] = __builtin_amdgcn_mfma_f32_16x16x32_f16(af, bf, a2[tt], 0, 0, 0);
            }
        }
        #pragma unroll
        for (int tt = 0; tt < 2; ++tt) {
            const int c = tt * 16 + l15;               // depth 0..31
            const float bb = bq[h * 32 + c];
            #pragma unroll
            for (int r = 0; r < 4; ++r) {
                const int lc = quad * 4 + r;           // row within 16-group
                sm.a.Qs[((size_t)w * 64 + (c >> 3) * 16 + lc) * 8 + (c & 7)] =
                    (f16)((a2[tt][r] + bb) * SCALE);
            }
        }
    }
    __syncthreads();
    h8 qf[4];
    #pragma unroll
    for (int qg = 0; qg < 4; ++qg)
        qf[qg] = *(const h8*)(sm.a.Qs + ((size_t)qg * 64 + lane) * 8);
    __syncthreads();   // Qs dead; union reused as Os/lS below

    // ---- split-K flash (wave w = keys [w*512,(w+1)*512)) ----
    const int* mrow = mask + b * Ln;
    const f16* Kh = S + (size_t)h * 65536;             // 128 groups x 512 f16
    const f16* Vh = S + VZB + (size_t)h * 65536;

    f4 o[2][4];
    #pragma unroll
    for (int i = 0; i < 2; ++i)
        #pragma unroll
        for (int j = 0; j < 4; ++j) o[i][j] = (f4){0.f, 0.f, 0.f, 0.f};
    float l_run[4] = {0.f, 0.f, 0.f, 0.f};
    const int k_base = w * (Ln / 4);

    for (int kt = 0; kt < Ln / 4 / 64; ++kt) {
        const int k0 = k_base + kt * 64;
        #pragma unroll
        for (int tt = 0; tt < 4; ++tt) {
            const int g = (k0 >> 4) + tt;              // group 0..127
            h8 kf = *(const h8*)(Kh + ((size_t)g * 64 + lane) * 8);
            const int4 mk = *(const int4*)(mrow + g * 16 + quad * 4);
            f4 bias4 = { mk.x ? 0.f : NEGC, mk.y ? 0.f : NEGC,
                         mk.z ? 0.f : NEGC, mk.w ? 0.f : NEGC };
            h4 va0 = *(const h4*)(Vh + ((size_t)(g * 2)     * 64 + lane) * 4);
            h4 va1 = *(const h4*)(Vh + ((size_t)(g * 2 + 1) * 64 + lane) * 4);
            f4 s_[4];
            #pragma unroll
            for (int qg = 0; qg < 4; ++qg)
                s_[qg] = __builtin_amdgcn_mfma_f32_16x16x32_f16(kf, qf[qg], bias4, 0, 0, 0);
            #pragma unroll
            for (int qg = 0; qg < 4; ++qg) {
                h4 pf;
                #pragma unroll
                for (int r = 0; r < 4; ++r) {
                    const float pv = __expf(s_[qg][r]);
                    l_run[qg] += pv;
                    pf[r] = (f16)pv;
                }
                o[0][qg] = __builtin_amdgcn_mfma_f32_16x16x16f16(va0, pf, o[0][qg], 0, 0, 0);
                o[1][qg] = __builtin_amdgcn_mfma_f32_16x16x16f16(va1, pf, o[1][qg], 0, 0, 0);
            }
        }
    }
    // ---- wave partials ----
    #pragma unroll
    for (int qg = 0; qg < 4; ++qg) {
        l_run[qg] += __shfl_xor(l_run[qg], 16, 64);
        l_run[qg] += __shfl_xor(l_run[qg], 32, 64);
        if (quad == 0) sm.c.lS[w][qg * 16 + l15] = l_run[qg];
        #pragma unroll
        for (int dg = 0; dg < 2; ++dg)
            #pragma unroll
            for (int r = 0; r < 4; ++r)
                sm.c.Os[w][dg * 16 + quad * 4 + r][qg * 16 + l15] = o[dg][qg][r];
    }
    __syncthreads();

    // ---- combine 4 split-K chunks -> Oz chunk write ----
    const int cq = t & 63, dv = t >> 6;
    const float ls = sm.c.lS[0][cq] + sm.c.lS[1][cq] + sm.c.lS[2][cq] + sm.c.lS[3][cq];
    const float inv = 1.0f / ls;
    h8 pack;
    #pragma unroll
    for (int i = 0; i < 8; ++i) {
        const int dd = dv * 8 + i;
        const float ov = sm.c.Os[0][dd][cq] + sm.c.Os[1][dd][cq] +
                         sm.c.Os[2][dd][cq] + sm.c.Os[3][dd][cq];
        pack[i] = (f16)(ov * inv);
    }
    const int gm = b * 128 + ((q0 + cq) >> 4);         // GLOBAL row group
    *(h8*)(S + OZB + (((size_t)gm * 8 + h) * 64 + dv * 16 + (cq & 15)) * 8) = pack;
}

// ---- out projection for rows [rowStart, rowStart + 64*gridDim.x). ---------
__global__ __launch_bounds__(256) void outproj(
    const float* __restrict__ Wo, const float* __restrict__ bo,
    float* outbuf, int rowStart)
{
    __shared__ f16 Wl[64 * WLS];
    f16* S = (f16*)outbuf;
    const int t = threadIdx.x, w = t >> 6, lane = t & 63;
    const int l15 = lane & 15, quad = lane >> 4;
    const int m0 = rowStart + blockIdx.x * 64 + w * 16;
    const int n0 = blockIdx.y * 64;

    {
        const int nl = t & 63, kb = t >> 6;
        for (int kk = 0; kk < 64; ++kk) {
            const int k = kk * 4 + kb;
            Wl[nl * WLS + k] = (f16)Wo[(size_t)k * DIN + n0 + nl];
        }
    }
    __syncthreads();

    const int gm = m0 >> 4;
    f4 acc[4] = {{0.f,0.f,0.f,0.f},{0.f,0.f,0.f,0.f},{0.f,0.f,0.f,0.f},{0.f,0.f,0.f,0.f}};
    for (int k0 = 0; k0 < DIN; k0 += 32) {
        const int h = k0 >> 5;
        h8 af = *(const h8*)(S + OZB + (((size_t)gm * 8 + h) * 64 + lane) * 8);
        #pragma unroll
        for (int tt = 0; tt < 4; ++tt) {
            h8 bf = *(const h8*)(Wl + (tt * 16 + l15) * WLS + k0 + quad * 8);
            acc[tt] = __builtin_amdgcn_mfma_f32_16x16x32_f16(af, bf, acc[tt], 0, 0, 0);
        }
    }
    #pragma unroll
    for (int tt = 0; tt < 4; ++tt) {
        const int c = n0 + tt * 16 + l15;
        const float bb = bo[c];
        #pragma unroll
        for (int r = 0; r < 4; ++r)
            outbuf[(size_t)(m0 + quad * 4 + r) * DIN + c] = acc[tt][r] + bb;
    }
}

// ---- single-block tail: rows 4032..4095 (write region overlaps own Oz). ---
__global__ __launch_bounds__(256) void out_tail(
    const float* __restrict__ Wo, const float* __restrict__ bo, float* outbuf)
{
    __shared__ f16 Wl3[256 * 40];            // [n=256][kpad=40] f16 = 20 KB
    f16* S = (f16*)outbuf;
    const int t = threadIdx.x, w = t >> 6, lane = t & 63;
    const int l15 = lane & 15, quad = lane >> 4;
    const int gm = 252 + w;                  // wave w -> rows 4032 + w*16

    h8 af[8];                                // all 8 head-chunks of own Oz rows
    #pragma unroll
    for (int h = 0; h < 8; ++h)
        af[h] = *(const h8*)(S + OZB + (((size_t)gm * 8 + h) * 64 + lane) * 8);
    __syncthreads();                         // everyone holds Oz before overwrite

    f4 acc[16];
    #pragma unroll
    for (int tt = 0; tt < 16; ++tt) acc[tt] = (f4){0.f, 0.f, 0.f, 0.f};

    for (int h = 0; h < 8; ++h) {
        __syncthreads();                     // previous chunk's bf reads done
        for (int i = t; i < 32 * 256; i += 256) {     // stage Wo k-chunk
            const int kb = i >> 8, n = i & 255;
            Wl3[n * 40 + kb] = (f16)Wo[(size_t)(h * 32 + kb) * DIN + n];
        }
        __syncthreads();
        #pragma unroll
        for (int tt = 0; tt < 16; ++tt) {
            h8 bf = *(const h8*)(Wl3 + (size_t)(tt * 16 + l15) * 40 + quad * 8);
            acc[tt] = __builtin_amdgcn_mfma_f32_16x16x32_f16(af[h], bf, acc[tt], 0, 0, 0);
        }
    }
    #pragma unroll
    for (int tt = 0; tt < 16; ++tt) {
        const int c = tt * 16 + l15;
        const float bb = bo[c];
        #pragma unroll
        for (int r = 0; r < 4; ++r)
            outbuf[(size_t)(4032 + w * 16 + quad * 4 + r) * DIN + c] = acc[tt][r] + bb;
    }
}

// ===========================================================================
extern "C" void kernel_launch(void* const* d_in, const int* in_sizes, int n_in,
                              void* d_out, int out_size, void* d_ws, size_t ws_size,
                              hipStream_t stream) {
    (void)in_sizes; (void)n_in; (void)d_ws; (void)ws_size; (void)out_size;
    const float* Xq = (const float*)d_in[0];
    const float* Xk = (const float*)d_in[1];
    const float* Xv = (const float*)d_in[2];
    const int*  mask = (const int*)d_in[3];
    const float* Wq = (const float*)d_in[4];
    const float* bq = (const float*)d_in[5];
    const float* Wk = (const float*)d_in[6];
    const float* bk = (const float*)d_in[7];
    const float* Wv = (const float*)d_in[8];
    const float* bv = (const float*)d_in[9];
    const float* Wo = (const float*)d_in[10];
    const float* bo = (const float*)d_in[11];
    float* out = (float*)d_out;
    f16* S = (f16*)out;

    // ZERO workspace; device-wide sync + coherence from kernel boundaries.
    projKV<<<dim3(16, 4, 2), 256, 0, stream>>>(Xk, Xv, Wk, Wv, bk, bv, S, 0);
    flashQ<<<dim3(8, 32), 256, 0, stream>>>(Xq, Wq, bq, mask, out, 0);
    projKV<<<dim3(16, 4, 2), 256, 0, stream>>>(Xk, Xv, Wk, Wv, bk, bv, S, 1);
    flashQ<<<dim3(8, 32), 256, 0, stream>>>(Xq, Wq, bq, mask, out, 1);

    outproj<<<dim3(32, 4), 256, 0, stream>>>(Wo, bo, out, 0);      // rows    0..2047
    outproj<<<dim3(16, 4), 256, 0, stream>>>(Wo, bo, out, 2048);   // rows 2048..3071
    outproj<<<dim3( 8, 4), 256, 0, stream>>>(Wo, bo, out, 3072);   // rows 3072..3583
    outproj<<<dim3( 4, 4), 256, 0, stream>>>(Wo, bo, out, 3584);   // rows 3584..3839
    outproj<<<dim3( 2, 4), 256, 0, stream>>>(Wo, bo, out, 3840);   // rows 3840..3967
    outproj<<<dim3( 1, 4), 256, 0, stream>>>(Wo, bo, out, 3968);   // rows 3968..4031
    out_tail<<<1, 256, 0, stream>>>(Wo, bo, out);                  // rows 4032..4095
}

// Round 3
// 188.122 us; speedup vs baseline: 1.9208x; 1.2182x over previous
//
#include <hip/hip_runtime.h>

#define Bn 2
#define Ln 2048
#define DIN 256
#define Hn 8
#define DEPTH 32
#define SCALE 0.17677669529663687f      // 1/sqrt(32)
#define NEGC (-4294967296.0f)           // float32(-2^32+1)
#define WLS 264                         // LDS W^T row stride (f16)

typedef _Float16 f16;
typedef _Float16 h8 __attribute__((ext_vector_type(8)));   // K=32 A/B frag
typedef _Float16 h4 __attribute__((ext_vector_type(4)));   // K=16 A/B frag
typedef float f4 __attribute__((ext_vector_type(4)));      // C/D frag

// ===========================================================================
// SELF-ALIASING ZERO-WORKSPACE LAYOUT in d_out (4 MB = 2M f16 = 64 chunks
// of 64 KB; chunk a = output rows [64a, 64a+64)):
//   lower half of chunk a  (elements a*32768 + [0,16384)):
//       Oz of rows [64a,64a+64): sub-chunk (s,h) at a*32768 + (s*8+h)*512,
//       s = (row>>4)&3, layout [dv][r15][j] (A-frag order).
//   upper half = "hole" page  (elements a*32768 + 16384 + [0,16384)):
//       K/V of the CURRENT batch, flat index j in [0,1M):
//       addr(j) = ((j>>14)<<15) + 16384 + (j&16383);  K = j<512K, V = 512K+j.
// Schedule (5 launches; sync/coherence purely from kernel boundaries):
//   L1 projKV(b0)->holes   L2 flashQ(b0): reads holes, Oz0 -> lower 0..31
//   L3 projKV(b1)->holes   L4 flashQ(b1): reads holes, Oz1 -> lower 32..63
//   L5 outproj, 64 blocks: block a reads its own Oz (regs), syncs, writes
//      its full 64 KB chunk.  No launch writes anything another concurrent
//      block still reads.
// ===========================================================================

// ---- K/V projection GEMM for one batch into the hole pages. ---------------
__global__ __launch_bounds__(256) void projKV(
    const float* __restrict__ Xk, const float* __restrict__ Xv,
    const float* __restrict__ Wk, const float* __restrict__ Wv,
    const float* __restrict__ bk, const float* __restrict__ bv,
    f16* S, int b)
{
    __shared__ f16 Wl[64 * WLS];             // 33.8 KB: W^T tile [n_local][k]
    const int p = blockIdx.z;                // 0 -> K, 1 -> V
    const float* X = (p ? Xv : Xk) + (size_t)b * Ln * DIN;
    const float* W = p ? Wv : Wk;
    const float* bias = p ? bv : bk;

    const int t = threadIdx.x, w = t >> 6, lane = t & 63;
    const int l15 = lane & 15, quad = lane >> 4;
    const int n0 = blockIdx.y * 64;

    {   // stage W[k][n0+nl] -> Wl[nl][k] (f16); coalesced 256B global rows
        const int nl = t & 63, kb = t >> 6;
        for (int kk = 0; kk < 64; ++kk) {
            const int k = kk * 4 + kb;
            Wl[nl * WLS + k] = (f16)W[(size_t)k * DIN + n0 + nl];
        }
    }
    __syncthreads();

    const int m0w = blockIdx.x * 128 + w * 32;
    const float* A0 = X + (size_t)(m0w + l15) * DIN;
    const float* A1 = X + (size_t)(m0w + 16 + l15) * DIN;

    f4 acc[2][4];
    #pragma unroll
    for (int mi = 0; mi < 2; ++mi)
        #pragma unroll
        for (int tt = 0; tt < 4; ++tt) acc[mi][tt] = (f4){0.f, 0.f, 0.f, 0.f};

    for (int k0 = 0; k0 < DIN; k0 += 32) {
        float4 xa0 = *(const float4*)(A0 + k0 + quad * 8);
        float4 xb0 = *(const float4*)(A0 + k0 + quad * 8 + 4);
        float4 xa1 = *(const float4*)(A1 + k0 + quad * 8);
        float4 xb1 = *(const float4*)(A1 + k0 + quad * 8 + 4);
        h8 af0 = { (f16)xa0.x, (f16)xa0.y, (f16)xa0.z, (f16)xa0.w,
                   (f16)xb0.x, (f16)xb0.y, (f16)xb0.z, (f16)xb0.w };
        h8 af1 = { (f16)xa1.x, (f16)xa1.y, (f16)xa1.z, (f16)xa1.w,
                   (f16)xb1.x, (f16)xb1.y, (f16)xb1.z, (f16)xb1.w };
        #pragma unroll
        for (int tt = 0; tt < 4; ++tt) {
            h8 bf = *(const h8*)(Wl + (tt * 16 + l15) * WLS + k0 + quad * 8);
            acc[0][tt] = __builtin_amdgcn_mfma_f32_16x16x32_f16(af0, bf, acc[0][tt], 0, 0, 0);
            acc[1][tt] = __builtin_amdgcn_mfma_f32_16x16x32_f16(af1, bf, acc[1][tt], 0, 0, 0);
        }
    }
    #pragma unroll
    for (int mi = 0; mi < 2; ++mi)
        #pragma unroll
        for (int tt = 0; tt < 4; ++tt) {
            const int c = n0 + tt * 16 + l15;     // 16-tile never straddles a head
            const float bb = bias[c];
            const int h = c >> 5, dd = c & 31;
            #pragma unroll
            for (int r = 0; r < 4; ++r) {
                const int l = m0w + mi * 16 + quad * 4 + r;   // 0..2047 in-batch
                const float v = acc[mi][tt][r] + bb;
                const unsigned hg = (unsigned)h * 128 + (l >> 4);
                unsigned j;
                if (!p)     // K swizzled (K=32 A-frag chunks), flat [0,512K)
                    j = (hg * 64 + (unsigned)(dd >> 3) * 16 + (l & 15)) * 8 + (dd & 7);
                else        // V swizzled (K=16 A-frag, 2 d-halves), flat 512K+[0,512K)
                    j = 524288u + ((hg * 2 + (dd >> 4)) * 64
                        + (unsigned)((l & 15) >> 2) * 16 + (dd & 15)) * 4 + (l & 3);
                S[(((size_t)(j >> 14)) << 15) + 16384u + (j & 16383u)] = (f16)v;
            }
        }
}

// ---- Q-proj (LDS-staged Wq) + split-K MFMA flash for one batch. -----------
__global__ __launch_bounds__(256) void flashQ(
    const float* __restrict__ Xq, const float* __restrict__ Wq,
    const float* __restrict__ bq, const int* __restrict__ mask,
    float* outbuf, int b)                     // aliases scratch - no restrict
{
    __shared__ union {
        struct { f16 Wlq[32 * WLS]; f16 Qs[2048]; } a;        // 21.0 KB
        struct { float Os[4][32][68]; float lS[4][64]; } c;   // 35.8 KB
    } sm;
    f16* S = (f16*)outbuf;
    const int t = threadIdx.x, w = t >> 6, lane = t & 63;
    const int l15 = lane & 15, quad = lane >> 4;
    const int h = blockIdx.x, q0 = blockIdx.y * 64;

    {   // stage Wq[:, h*32 + nl] -> Wlq[nl][k]; coalesced 128B row segments
        const int nl = t & 31, kb = t >> 5;
        for (int kk = 0; kk < 32; ++kk) {
            const int k = kk * 8 + kb;
            sm.a.Wlq[nl * WLS + k] = (f16)Wq[(size_t)k * DIN + h * 32 + nl];
        }
    }
    __syncthreads();

    {   // Q-proj: 64 rows x 32 cols, K=256, MFMA
        const float* A0 = Xq + (size_t)(b * Ln + q0 + w * 16 + l15) * DIN;
        f4 a2[2] = { {0.f,0.f,0.f,0.f}, {0.f,0.f,0.f,0.f} };
        #pragma unroll
        for (int kk = 0; kk < 8; ++kk) {
            const int k0 = kk * 32;
            float4 xa = *(const float4*)(A0 + k0 + quad * 8);
            float4 xb = *(const float4*)(A0 + k0 + quad * 8 + 4);
            h8 af = { (f16)xa.x, (f16)xa.y, (f16)xa.z, (f16)xa.w,
                      (f16)xb.x, (f16)xb.y, (f16)xb.z, (f16)xb.w };
            #pragma unroll
            for (int tt = 0; tt < 2; ++tt) {
                h8 bf = *(const h8*)(sm.a.Wlq + (tt * 16 + l15) * WLS + k0 + quad * 8);
                a2[tt] = __builtin_amdgcn_mfma_f32_16x16x32_f16(af, bf, a2[tt], 0, 0, 0);
            }
        }
        #pragma unroll
        for (int tt = 0; tt < 2; ++tt) {
            const int c = tt * 16 + l15;               // depth 0..31
            const float bb = bq[h * 32 + c];
            #pragma unroll
            for (int r = 0; r < 4; ++r) {
                const int lc = quad * 4 + r;           // row within 16-group
                sm.a.Qs[((size_t)w * 64 + (c >> 3) * 16 + lc) * 8 + (c & 7)] =
                    (f16)((a2[tt][r] + bb) * SCALE);
            }
        }
    }
    __syncthreads();
    h8 qf[4];
    #pragma unroll
    for (int qg = 0; qg < 4; ++qg)
        qf[qg] = *(const h8*)(sm.a.Qs + ((size_t)qg * 64 + lane) * 8);
    __syncthreads();   // Qs dead; union reused as Os/lS below

    // ---- split-K flash (wave w = keys [w*512,(w+1)*512)) ----
    const int* mrow = mask + b * Ln;

    f4 o[2][4];
    #pragma unroll
    for (int i = 0; i < 2; ++i)
        #pragma unroll
        for (int j = 0; j < 4; ++j) o[i][j] = (f4){0.f, 0.f, 0.f, 0.f};
    float l_run[4] = {0.f, 0.f, 0.f, 0.f};
    const int k_base = w * (Ln / 4);

    for (int kt = 0; kt < Ln / 4 / 64; ++kt) {
        const int k0 = k_base + kt * 64;
        #pragma unroll
        for (int tt = 0; tt < 4; ++tt) {
            const int g = (k0 >> 4) + tt;              // group 0..127
            // K page: h*4 + (g>>5); in-page ((g&31)*64 + lane)*8
            const size_t kaddr = ((size_t)(h * 4 + (g >> 5)) << 15) + 16384u
                               + (size_t)((g & 31) * 64 + lane) * 8;
            h8 kf = *(const h8*)(S + kaddr);
            const int4 mk = *(const int4*)(mrow + g * 16 + quad * 4);
            f4 bias4 = { mk.x ? 0.f : NEGC, mk.y ? 0.f : NEGC,
                         mk.z ? 0.f : NEGC, mk.w ? 0.f : NEGC };
            // V page: 32 + h*4 + (g>>5); in-page (g&31)*512 + lane*4 (+256)
            const size_t vaddr = ((size_t)(32 + h * 4 + (g >> 5)) << 15) + 16384u
                               + (size_t)(g & 31) * 512 + lane * 4;
            h4 va0 = *(const h4*)(S + vaddr);
            h4 va1 = *(const h4*)(S + vaddr + 256);
            f4 s_[4];
            #pragma unroll
            for (int qg = 0; qg < 4; ++qg)
                s_[qg] = __builtin_amdgcn_mfma_f32_16x16x32_f16(kf, qf[qg], bias4, 0, 0, 0);
            #pragma unroll
            for (int qg = 0; qg < 4; ++qg) {
                h4 pf;
                #pragma unroll
                for (int r = 0; r < 4; ++r) {
                    const float pv = __expf(s_[qg][r]);
                    l_run[qg] += pv;
                    pf[r] = (f16)pv;
                }
                o[0][qg] = __builtin_amdgcn_mfma_f32_16x16x16f16(va0, pf, o[0][qg], 0, 0, 0);
                o[1][qg] = __builtin_amdgcn_mfma_f32_16x16x16f16(va1, pf, o[1][qg], 0, 0, 0);
            }
        }
    }
    // ---- wave partials ----
    #pragma unroll
    for (int qg = 0; qg < 4; ++qg) {
        l_run[qg] += __shfl_xor(l_run[qg], 16, 64);
        l_run[qg] += __shfl_xor(l_run[qg], 32, 64);
        if (quad == 0) sm.c.lS[w][qg * 16 + l15] = l_run[qg];
        #pragma unroll
        for (int dg = 0; dg < 2; ++dg)
            #pragma unroll
            for (int r = 0; r < 4; ++r)
                sm.c.Os[w][dg * 16 + quad * 4 + r][qg * 16 + l15] = o[dg][qg][r];
    }
    __syncthreads();

    // ---- combine 4 split-K chunks -> Oz chunk write (self-aliased slot) ----
    const int cq = t & 63, dv = t >> 6;
    const float ls = sm.c.lS[0][cq] + sm.c.lS[1][cq] + sm.c.lS[2][cq] + sm.c.lS[3][cq];
    const float inv = 1.0f / ls;
    h8 pack;
    #pragma unroll
    for (int i = 0; i < 8; ++i) {
        const int dd = dv * 8 + i;
        const float ov = sm.c.Os[0][dd][cq] + sm.c.Os[1][dd][cq] +
                         sm.c.Os[2][dd][cq] + sm.c.Os[3][dd][cq];
        pack[i] = (f16)(ov * inv);
    }
    const int gm = b * 128 + ((q0 + cq) >> 4);         // GLOBAL row group
    const int a = gm >> 2, s = gm & 3;                 // chunk, sub-group
    *(h8*)(S + (size_t)a * 32768 + (size_t)((s * 8 + h) * 64 + dv * 16 + (cq & 15)) * 8)
        = pack;
}

// ---- Single-launch out projection: block a owns chunk a (64 rows). --------
__global__ __launch_bounds__(512) void outproj(
    const float* __restrict__ Wo, const float* __restrict__ bo, float* outbuf)
{
    __shared__ f16 Wl3[256 * 40];            // [n=256][kpad=40] f16 = 20 KB
    f16* S = (f16*)outbuf;
    const int t = threadIdx.x, w = t >> 6, lane = t & 63;
    const int l15 = lane & 15, quad = lane >> 4;
    const int a = blockIdx.x;
    const int s = w >> 1, nh = w & 1;        // wave -> (row-group, n-half)

    h8 af[8];                                // own Oz rows -> regs BEFORE writes
    #pragma unroll
    for (int h = 0; h < 8; ++h)
        af[h] = *(const h8*)(S + (size_t)a * 32768
                             + (size_t)((s * 8 + h) * 64 + lane) * 8);
    __syncthreads();                         // all waves hold Oz before overwrite

    f4 acc[8];
    #pragma unroll
    for (int tt = 0; tt < 8; ++tt) acc[tt] = (f4){0.f, 0.f, 0.f, 0.f};

    for (int h = 0; h < 8; ++h) {
        __syncthreads();                     // previous chunk's bf reads done
        for (int i = t; i < 32 * 256; i += 512) {     // stage Wo k-chunk
            const int kb = i >> 8, n = i & 255;
            Wl3[n * 40 + kb] = (f16)Wo[(size_t)(h * 32 + kb) * DIN + n];
        }
        __syncthreads();
        #pragma unroll
        for (int tt = 0; tt < 8; ++tt) {
            h8 bf = *(const h8*)(Wl3 + (size_t)(nh * 128 + tt * 16 + l15) * 40 + quad * 8);
            acc[tt] = __builtin_amdgcn_mfma_f32_16x16x32_f16(af[h], bf, acc[tt], 0, 0, 0);
        }
    }
    #pragma unroll
    for (int tt = 0; tt < 8; ++tt) {
        const int c = nh * 128 + tt * 16 + l15;
        const float bb = bo[c];
        #pragma unroll
        for (int r = 0; r < 4; ++r)
            outbuf[(size_t)(a * 64 + s * 16 + quad * 4 + r) * DIN + c] = acc[tt][r] + bb;
    }
}

// ===========================================================================
extern "C" void kernel_launch(void* const* d_in, const int* in_sizes, int n_in,
                              void* d_out, int out_size, void* d_ws, size_t ws_size,
                              hipStream_t stream) {
    (void)in_sizes; (void)n_in; (void)d_ws; (void)ws_size; (void)out_size;
    const float* Xq = (const float*)d_in[0];
    const float* Xk = (const float*)d_in[1];
    const float* Xv = (const float*)d_in[2];
    const int*  mask = (const int*)d_in[3];
    const float* Wq = (const float*)d_in[4];
    const float* bq = (const float*)d_in[5];
    const float* Wk = (const float*)d_in[6];
    const float* bk = (const float*)d_in[7];
    const float* Wv = (const float*)d_in[8];
    const float* bv = (const float*)d_in[9];
    const float* Wo = (const float*)d_in[10];
    const float* bo = (const float*)d_in[11];
    float* out = (float*)d_out;
    f16* S = (f16*)out;

    // ZERO workspace; 5 launches; coherence purely from kernel boundaries.
    projKV<<<dim3(16, 4, 2), 256, 0, stream>>>(Xk, Xv, Wk, Wv, bk, bv, S, 0);
    flashQ<<<dim3(8, 32), 256, 0, stream>>>(Xq, Wq, bq, mask, out, 0);
    projKV<<<dim3(16, 4, 2), 256, 0, stream>>>(Xk, Xv, Wk, Wv, bk, bv, S, 1);
    flashQ<<<dim3(8, 32), 256, 0, stream>>>(Xq, Wq, bq, mask, out, 1);
    outproj<<<64, 512, 0, stream>>>(Wo, bo, out);
}

// Round 4
// 140.044 us; speedup vs baseline: 2.5803x; 1.3433x over previous
//
#include <hip/hip_runtime.h>

#define Bn 2
#define Ln 2048
#define DIN 256
#define Hn 8
#define DEPTH 32
#define SCALE 0.17677669529663687f      // 1/sqrt(32)
#define NEGC (-4294967296.0f)           // float32(-2^32+1)
#define WLS 264                         // LDS W^T row stride (f16)

typedef _Float16 f16;
typedef _Float16 h8 __attribute__((ext_vector_type(8)));   // K=32 A/B frag
typedef _Float16 h4 __attribute__((ext_vector_type(4)));   // K=16 A/B frag
typedef float f4 __attribute__((ext_vector_type(4)));      // C/D frag

// ===========================================================================
// FINE-GRAINED SELF-ALIASING LAYOUT in d_out (4 MB = 2M f16 = 256 pages of
// 8192 f16 = 16 KB; page g = output rows [16g, 16g+16)):
//   lower half of page g (f16 g*8192 + [0,4096)):
//       Oz of rows [16g,16g+16): head h slot at g*8192 + (h*64 + frag)*8,
//       frag = dv*16 + r15 (A-frag order), 8 f16 each.
//   upper half = hole (f16 g*8192 + 4096 + [0,4096)):
//       K/V of the CURRENT batch, flat index j in [0,1M):
//       addr(j) = ((j>>12)<<13) + 4096 + (j&4095);  K = j<512K, V = 512K+j.
//       => K of (head h, group g16) at page h*16+(g16>>3), in-hole
//          (g16&7)*512 + lane*8;  V at page 128+h*16+(g16>>3), same +-256.
// Schedule (5 launches; sync/coherence purely from kernel boundaries):
//   L1 projKV(b0)->holes   L2 flashQ(b0): reads holes, Oz0 -> lower 0..127
//   L3 projKV(b1)->holes   L4 flashQ(b1): reads holes, Oz1 -> lower 128..255
//   L5 outproj, 256 blocks: block g reads its own Oz page (regs), syncs,
//      writes its full 16 KB page.  No cross-block read/write overlap ever:
//      Oz writes (lower) vs hole reads (upper) are disjoint byte ranges
//      8 KB apart; outproj block g is the only block touching page g.
// ===========================================================================

// ---- K/V projection GEMM for one batch into the hole halves. --------------
__global__ __launch_bounds__(256) void projKV(
    const float* __restrict__ Xk, const float* __restrict__ Xv,
    const float* __restrict__ Wk, const float* __restrict__ Wv,
    const float* __restrict__ bk, const float* __restrict__ bv,
    f16* S, int b)
{
    __shared__ f16 Wl[64 * WLS];             // 33.8 KB: W^T tile [n_local][k]
    const int p = blockIdx.z;                // 0 -> K, 1 -> V
    const float* X = (p ? Xv : Xk) + (size_t)b * Ln * DIN;
    const float* W = p ? Wv : Wk;
    const float* bias = p ? bv : bk;

    const int t = threadIdx.x, w = t >> 6, lane = t & 63;
    const int l15 = lane & 15, quad = lane >> 4;
    const int n0 = blockIdx.y * 64;

    {   // stage W[k][n0+nl] -> Wl[nl][k] (f16); coalesced 256B global rows
        const int nl = t & 63, kb = t >> 6;
        for (int kk = 0; kk < 64; ++kk) {
            const int k = kk * 4 + kb;
            Wl[nl * WLS + k] = (f16)W[(size_t)k * DIN + n0 + nl];
        }
    }
    __syncthreads();

    const int m0w = blockIdx.x * 128 + w * 32;
    const float* A0 = X + (size_t)(m0w + l15) * DIN;
    const float* A1 = X + (size_t)(m0w + 16 + l15) * DIN;

    f4 acc[2][4];
    #pragma unroll
    for (int mi = 0; mi < 2; ++mi)
        #pragma unroll
        for (int tt = 0; tt < 4; ++tt) acc[mi][tt] = (f4){0.f, 0.f, 0.f, 0.f};

    for (int k0 = 0; k0 < DIN; k0 += 32) {
        float4 xa0 = *(const float4*)(A0 + k0 + quad * 8);
        float4 xb0 = *(const float4*)(A0 + k0 + quad * 8 + 4);
        float4 xa1 = *(const float4*)(A1 + k0 + quad * 8);
        float4 xb1 = *(const float4*)(A1 + k0 + quad * 8 + 4);
        h8 af0 = { (f16)xa0.x, (f16)xa0.y, (f16)xa0.z, (f16)xa0.w,
                   (f16)xb0.x, (f16)xb0.y, (f16)xb0.z, (f16)xb0.w };
        h8 af1 = { (f16)xa1.x, (f16)xa1.y, (f16)xa1.z, (f16)xa1.w,
                   (f16)xb1.x, (f16)xb1.y, (f16)xb1.z, (f16)xb1.w };
        #pragma unroll
        for (int tt = 0; tt < 4; ++tt) {
            h8 bf = *(const h8*)(Wl + (tt * 16 + l15) * WLS + k0 + quad * 8);
            acc[0][tt] = __builtin_amdgcn_mfma_f32_16x16x32_f16(af0, bf, acc[0][tt], 0, 0, 0);
            acc[1][tt] = __builtin_amdgcn_mfma_f32_16x16x32_f16(af1, bf, acc[1][tt], 0, 0, 0);
        }
    }
    #pragma unroll
    for (int mi = 0; mi < 2; ++mi)
        #pragma unroll
        for (int tt = 0; tt < 4; ++tt) {
            const int c = n0 + tt * 16 + l15;     // 16-tile never straddles a head
            const float bb = bias[c];
            const int h = c >> 5, dd = c & 31;
            #pragma unroll
            for (int r = 0; r < 4; ++r) {
                const int l = m0w + mi * 16 + quad * 4 + r;   // 0..2047 in-batch
                const float v = acc[mi][tt][r] + bb;
                const unsigned hg = (unsigned)h * 128 + (l >> 4);
                unsigned j;
                if (!p)     // K swizzled (K=32 A-frag chunks), flat [0,512K)
                    j = (hg * 64 + (unsigned)(dd >> 3) * 16 + (l & 15)) * 8 + (dd & 7);
                else        // V swizzled (K=16 A-frag, 2 d-halves), flat 512K+[0,512K)
                    j = 524288u + ((hg * 2 + (dd >> 4)) * 64
                        + (unsigned)((l & 15) >> 2) * 16 + (dd & 15)) * 4 + (l & 3);
                S[(((size_t)(j >> 12)) << 13) + 4096u + (j & 4095u)] = (f16)v;
            }
        }
}

// ---- Q-proj (LDS-staged Wq) + 8-way split-K MFMA flash for one batch. -----
__global__ __launch_bounds__(512) void flashQ(
    const float* __restrict__ Xq, const float* __restrict__ Wq,
    const float* __restrict__ bq, const int* __restrict__ mask,
    float* outbuf, int b)                     // aliases scratch - no restrict
{
    __shared__ union {
        struct { f16 Wlq[32 * WLS]; f16 Qs[2048]; } a;        // 21.0 KB
        struct { float Os[8][32][68]; float lS[8][64]; } c;   // 71.7 KB
    } sm;
    f16* S = (f16*)outbuf;
    const int t = threadIdx.x, w = t >> 6, lane = t & 63;
    const int l15 = lane & 15, quad = lane >> 4;
    const int h = blockIdx.x, q0 = blockIdx.y * 64;

    {   // stage Wq[:, h*32 + nl] -> Wlq[nl][k]; coalesced 128B row segments
        const int nl = t & 31, kb = t >> 5;          // kb 0..15
        for (int kk = 0; kk < 16; ++kk) {
            const int k = kk * 16 + kb;
            sm.a.Wlq[nl * WLS + k] = (f16)Wq[(size_t)k * DIN + h * 32 + nl];
        }
    }
    __syncthreads();

    if (w < 4) {   // Q-proj: 64 rows x 32 cols, K=256, MFMA (waves 0..3)
        const float* A0 = Xq + (size_t)(b * Ln + q0 + w * 16 + l15) * DIN;
        f4 a2[2] = { {0.f,0.f,0.f,0.f}, {0.f,0.f,0.f,0.f} };
        #pragma unroll
        for (int kk = 0; kk < 8; ++kk) {
            const int k0 = kk * 32;
            float4 xa = *(const float4*)(A0 + k0 + quad * 8);
            float4 xb = *(const float4*)(A0 + k0 + quad * 8 + 4);
            h8 af = { (f16)xa.x, (f16)xa.y, (f16)xa.z, (f16)xa.w,
                      (f16)xb.x, (f16)xb.y, (f16)xb.z, (f16)xb.w };
            #pragma unroll
            for (int tt = 0; tt < 2; ++tt) {
                h8 bf = *(const h8*)(sm.a.Wlq + (tt * 16 + l15) * WLS + k0 + quad * 8);
                a2[tt] = __builtin_amdgcn_mfma_f32_16x16x32_f16(af, bf, a2[tt], 0, 0, 0);
            }
        }
        #pragma unroll
        for (int tt = 0; tt < 2; ++tt) {
            const int c = tt * 16 + l15;               // depth 0..31
            const float bb = bq[h * 32 + c];
            #pragma unroll
            for (int r = 0; r < 4; ++r) {
                const int lc = quad * 4 + r;           // row within 16-group
                sm.a.Qs[((size_t)w * 64 + (c >> 3) * 16 + lc) * 8 + (c & 7)] =
                    (f16)((a2[tt][r] + bb) * SCALE);
            }
        }
    }
    __syncthreads();
    h8 qf[4];
    #pragma unroll
    for (int qg = 0; qg < 4; ++qg)
        qf[qg] = *(const h8*)(sm.a.Qs + ((size_t)qg * 64 + lane) * 8);
    __syncthreads();   // Qs dead; union reused as Os/lS below

    // ---- 8-way split-K flash (wave w = keys [w*256,(w+1)*256)) ----
    const int* mrow = mask + b * Ln;

    f4 o[2][4];
    #pragma unroll
    for (int i = 0; i < 2; ++i)
        #pragma unroll
        for (int j = 0; j < 4; ++j) o[i][j] = (f4){0.f, 0.f, 0.f, 0.f};
    float l_run[4] = {0.f, 0.f, 0.f, 0.f};
    const int k_base = w * (Ln / 8);

    for (int kt = 0; kt < Ln / 8 / 64; ++kt) {         // 4 iters
        const int k0 = k_base + kt * 64;
        #pragma unroll
        for (int tt = 0; tt < 4; ++tt) {
            const int g = (k0 >> 4) + tt;              // group 0..127
            // K: page h*16+(g>>3), in-hole (g&7)*512 + lane*8
            const size_t kaddr = ((size_t)(h * 16 + (g >> 3)) << 13) + 4096u
                               + (size_t)((g & 7) * 512 + lane * 8);
            h8 kf = *(const h8*)(S + kaddr);
            const int4 mk = *(const int4*)(mrow + g * 16 + quad * 4);
            f4 bias4 = { mk.x ? 0.f : NEGC, mk.y ? 0.f : NEGC,
                         mk.z ? 0.f : NEGC, mk.w ? 0.f : NEGC };
            // V: page 128+h*16+(g>>3), in-hole (g&7)*512 + lane*4 (+256)
            const size_t vaddr = ((size_t)(128 + h * 16 + (g >> 3)) << 13) + 4096u
                               + (size_t)((g & 7) * 512 + lane * 4);
            h4 va0 = *(const h4*)(S + vaddr);
            h4 va1 = *(const h4*)(S + vaddr + 256);
            f4 s_[4];
            #pragma unroll
            for (int qg = 0; qg < 4; ++qg)
                s_[qg] = __builtin_amdgcn_mfma_f32_16x16x32_f16(kf, qf[qg], bias4, 0, 0, 0);
            #pragma unroll
            for (int qg = 0; qg < 4; ++qg) {
                h4 pf;
                #pragma unroll
                for (int r = 0; r < 4; ++r) {
                    const float pv = __expf(s_[qg][r]);
                    l_run[qg] += pv;
                    pf[r] = (f16)pv;
                }
                o[0][qg] = __builtin_amdgcn_mfma_f32_16x16x16f16(va0, pf, o[0][qg], 0, 0, 0);
                o[1][qg] = __builtin_amdgcn_mfma_f32_16x16x16f16(va1, pf, o[1][qg], 0, 0, 0);
            }
        }
    }
    // ---- wave partials ----
    #pragma unroll
    for (int qg = 0; qg < 4; ++qg) {
        l_run[qg] += __shfl_xor(l_run[qg], 16, 64);
        l_run[qg] += __shfl_xor(l_run[qg], 32, 64);
        if (quad == 0) sm.c.lS[w][qg * 16 + l15] = l_run[qg];
        #pragma unroll
        for (int dg = 0; dg < 2; ++dg)
            #pragma unroll
            for (int r = 0; r < 4; ++r)
                sm.c.Os[w][dg * 16 + quad * 4 + r][qg * 16 + l15] = o[dg][qg][r];
    }
    __syncthreads();

    // ---- combine 8 split-K chunks -> Oz page write (self-aliased slot) ----
    if (t < 256) {
        const int cq = t & 63, dv = t >> 6;            // dv 0..3
        float ls = 0.f;
        #pragma unroll
        for (int i = 0; i < 8; ++i) ls += sm.c.lS[i][cq];
        const float inv = 1.0f / ls;
        h8 pack;
        #pragma unroll
        for (int i = 0; i < 8; ++i) {
            const int dd = dv * 8 + i;
            float ov = 0.f;
            #pragma unroll
            for (int s = 0; s < 8; ++s) ov += sm.c.Os[s][dd][cq];
            pack[i] = (f16)(ov * inv);
        }
        const int gm = b * 128 + ((q0 + cq) >> 4);     // GLOBAL page index
        *(h8*)(S + (size_t)gm * 8192
               + (size_t)(h * 64 + dv * 16 + (cq & 15)) * 8) = pack;
    }
}

// ---- Single-launch out projection: block g owns page g (16 rows). ---------
// No LDS: A-frags from own Oz page, B-frags via 256 independent unrolled
// scalar Wo loads per thread (deep pipeline, no barrier-separated chains).
__global__ __launch_bounds__(256) void outproj(
    const float* __restrict__ Wo, const float* __restrict__ bo, float* outbuf)
{
    f16* S = (f16*)outbuf;
    const int t = threadIdx.x, w = t >> 6, lane = t & 63;
    const int l15 = lane & 15, quad = lane >> 4;
    const int g = blockIdx.x;                // page = 16-row group

    h8 af[8];                                // own Oz rows -> regs BEFORE writes
    #pragma unroll
    for (int h = 0; h < 8; ++h)
        af[h] = *(const h8*)(S + (size_t)g * 8192 + (size_t)(h * 64 + lane) * 8);
    __syncthreads();                         // all waves hold Oz before overwrite

    const float* Wop = Wo + w * 64 + l15;    // this wave's 64-col slice
    f4 acc[4] = {{0.f,0.f,0.f,0.f},{0.f,0.f,0.f,0.f},
                 {0.f,0.f,0.f,0.f},{0.f,0.f,0.f,0.f}};
    #pragma unroll
    for (int h = 0; h < 8; ++h) {
        h8 bf[4];
        #pragma unroll
        for (int tt = 0; tt < 4; ++tt)
            #pragma unroll
            for (int j = 0; j < 8; ++j)
                bf[tt][j] = (f16)Wop[(size_t)(h * 32 + quad * 8 + j) * DIN + tt * 16];
        #pragma unroll
        for (int tt = 0; tt < 4; ++tt)
            acc[tt] = __builtin_amdgcn_mfma_f32_16x16x32_f16(af[h], bf[tt], acc[tt], 0, 0, 0);
    }
    #pragma unroll
    for (int tt = 0; tt < 4; ++tt) {
        const int c = w * 64 + tt * 16 + l15;
        const float bb = bo[c];
        #pragma unroll
        for (int r = 0; r < 4; ++r)
            outbuf[(size_t)(g * 16 + quad * 4 + r) * DIN + c] = acc[tt][r] + bb;
    }
}

// ===========================================================================
extern "C" void kernel_launch(void* const* d_in, const int* in_sizes, int n_in,
                              void* d_out, int out_size, void* d_ws, size_t ws_size,
                              hipStream_t stream) {
    (void)in_sizes; (void)n_in; (void)d_ws; (void)ws_size; (void)out_size;
    const float* Xq = (const float*)d_in[0];
    const float* Xk = (const float*)d_in[1];
    const float* Xv = (const float*)d_in[2];
    const int*  mask = (const int*)d_in[3];
    const float* Wq = (const float*)d_in[4];
    const float* bq = (const float*)d_in[5];
    const float* Wk = (const float*)d_in[6];
    const float* bk = (const float*)d_in[7];
    const float* Wv = (const float*)d_in[8];
    const float* bv = (const float*)d_in[9];
    const float* Wo = (const float*)d_in[10];
    const float* bo = (const float*)d_in[11];
    float* out = (float*)d_out;
    f16* S = (f16*)out;

    // ZERO workspace; 5 launches; coherence purely from kernel boundaries.
    projKV<<<dim3(16, 4, 2), 256, 0, stream>>>(Xk, Xv, Wk, Wv, bk, bv, S, 0);
    flashQ<<<dim3(8, 32), 512, 0, stream>>>(Xq, Wq, bq, mask, out, 0);
    projKV<<<dim3(16, 4, 2), 256, 0, stream>>>(Xk, Xv, Wk, Wv, bk, bv, S, 1);
    flashQ<<<dim3(8, 32), 512, 0, stream>>>(Xq, Wq, bq, mask, out, 1);
    outproj<<<256, 256, 0, stream>>>(Wo, bo, out);
}

// Round 5
// 122.413 us; speedup vs baseline: 2.9519x; 1.1440x over previous
//
#include <hip/hip_runtime.h>

#define Bn 2
#define Ln 2048
#define DIN 256
#define Hn 8
#define DEPTH 32
#define SCALE 0.17677669529663687f      // 1/sqrt(32)
#define NEGC (-4294967296.0f)           // float32(-2^32+1)
#define NG  (Ln / 16)                   // 128 16-row groups per (b,h)
#define WLS 264                         // LDS W^T row stride (f16)

typedef _Float16 f16;
typedef _Float16 h8 __attribute__((ext_vector_type(8)));   // K=32 A/B frag
typedef _Float16 h4 __attribute__((ext_vector_type(4)));   // K=16 A/B frag
typedef float f4 __attribute__((ext_vector_type(4)));      // C/D frag

// ===========================================================================
// MAIN PATH (ws >= 8 MB; the harness's 268 MB ws poison-fill is UNCONDITIONAL
// -> using ws is free).  3 launches:
//   L1 proj_gemm (384 blk): QKV projections -> Qz (pre-scaled), Kz, Vz in ws
//   L2 flash_mfma (1024 blk): 32-q-row chunks, 4-way split-K -> Oz in ws
//   L3 out_gemm  (256 blk): no-LDS out-projection -> out
// Frag-swizzled ws layouts (proven in the 123.9us session kernel):
//   Qz/Kz chunk per (hb, 16-row group g) = 512 f16: lane(quad*16+l15) holds
//     8 f16 = row (g*16+l15), depth (quad*8..+7).
//   Vz per (hb,g): 2 half-chunks of 256 f16 (d-halves); lane holds 4 f16 =
//     V[key=g*16+quad*4+j][d=dhalf*16+l15].
//   Oz chunk per (row-group gm, h) = 512 f16: lane holds O[row=gm*16+l15]
//     [d=quad*8..+7].
// ===========================================================================

// ---- Kernel 1: QKV projection GEMM. Block: 128m x 64n, W^T staged in LDS.
__global__ __launch_bounds__(256) void proj_gemm(
    const float* __restrict__ Xq, const float* __restrict__ Xk, const float* __restrict__ Xv,
    const float* __restrict__ Wq, const float* __restrict__ Wk, const float* __restrict__ Wv,
    const float* __restrict__ bq, const float* __restrict__ bk, const float* __restrict__ bv,
    f16* __restrict__ Qz, f16* __restrict__ Kz, f16* __restrict__ Vz)
{
    __shared__ f16 Wl[64 * WLS];   // 33 KB: W^T tile [n_local][k]
    const int p = blockIdx.z;
    const float* X = p == 0 ? Xq : p == 1 ? Xk : Xv;
    const float* W = p == 0 ? Wq : p == 1 ? Wk : Wv;
    const float* bias = p == 0 ? bq : p == 1 ? bk : bv;

    const int t = threadIdx.x, w = t >> 6, lane = t & 63;
    const int l15 = lane & 15, quad = lane >> 4;
    const int n0 = blockIdx.y * 64;

    {   // stage W[k][n0+nl] -> Wl[nl][k] (f16); coalesced 256B global rows
        const int nl = t & 63, kb = t >> 6;
        for (int kk = 0; kk < 64; ++kk) {
            const int k = kk * 4 + kb;
            Wl[nl * WLS + k] = (f16)W[(size_t)k * DIN + n0 + nl];
        }
    }
    __syncthreads();

    const int m0w = blockIdx.x * 128 + w * 32;
    const float* A0 = X + (size_t)(m0w + l15) * DIN;
    const float* A1 = X + (size_t)(m0w + 16 + l15) * DIN;

    f4 acc[2][4];
    #pragma unroll
    for (int mi = 0; mi < 2; ++mi)
        #pragma unroll
        for (int tt = 0; tt < 4; ++tt) acc[mi][tt] = (f4){0.f, 0.f, 0.f, 0.f};

    for (int k0 = 0; k0 < DIN; k0 += 32) {
        float4 xa0 = *(const float4*)(A0 + k0 + quad * 8);
        float4 xb0 = *(const float4*)(A0 + k0 + quad * 8 + 4);
        float4 xa1 = *(const float4*)(A1 + k0 + quad * 8);
        float4 xb1 = *(const float4*)(A1 + k0 + quad * 8 + 4);
        h8 af0 = { (f16)xa0.x, (f16)xa0.y, (f16)xa0.z, (f16)xa0.w,
                   (f16)xb0.x, (f16)xb0.y, (f16)xb0.z, (f16)xb0.w };
        h8 af1 = { (f16)xa1.x, (f16)xa1.y, (f16)xa1.z, (f16)xa1.w,
                   (f16)xb1.x, (f16)xb1.y, (f16)xb1.z, (f16)xb1.w };
        #pragma unroll
        for (int tt = 0; tt < 4; ++tt) {
            h8 bf = *(const h8*)(Wl + (tt * 16 + l15) * WLS + k0 + quad * 8);
            acc[0][tt] = __builtin_amdgcn_mfma_f32_16x16x32_f16(af0, bf, acc[0][tt], 0, 0, 0);
            acc[1][tt] = __builtin_amdgcn_mfma_f32_16x16x32_f16(af1, bf, acc[1][tt], 0, 0, 0);
        }
    }
    #pragma unroll
    for (int mi = 0; mi < 2; ++mi)
        #pragma unroll
        for (int tt = 0; tt < 4; ++tt) {
            const int c = n0 + tt * 16 + l15;        // 16-tile never straddles a head
            const float bb = bias[c];
            const int h = c >> 5, dd = c & 31;
            #pragma unroll
            for (int r = 0; r < 4; ++r) {
                const int row = m0w + mi * 16 + quad * 4 + r;
                const int b = row >> 11, l = row & (Ln - 1);
                const float v = acc[mi][tt][r] + bb;
                const size_t hbg = (size_t)(b * Hn + h) * NG + (l >> 4);
                if (p == 0)        // Q swizzled (K=32 B-frag chunks), pre-scaled
                    Qz[(hbg * 64 + (dd >> 3) * 16 + (l & 15)) * 8 + (dd & 7)] =
                        (f16)(v * SCALE);
                else if (p == 1)   // K swizzled (K=32 A-frag chunks)
                    Kz[(hbg * 64 + (dd >> 3) * 16 + (l & 15)) * 8 + (dd & 7)] = (f16)v;
                else               // V swizzled (K=16 A-frag chunks, 2 d-halves)
                    Vz[((hbg * 2 + (dd >> 4)) * 64 + ((l & 15) >> 2) * 16 + (dd & 15)) * 4
                       + (l & 3)] = (f16)v;
            }
        }
}

// ---- Kernel 2: split-K MFMA flash, 32 q-rows/block for 2x TLP. ------------
// Grid (Ln/32=64, Bn*Hn=16): block = 32 q-rows; wave w = keys [w*512,(w+1)*512).
__global__ __launch_bounds__(256) void flash_mfma(
    const f16* __restrict__ Qz, const f16* __restrict__ Kz,
    const f16* __restrict__ Vz, const int* __restrict__ mask,
    f16* __restrict__ Oz)
{
    __shared__ float Os[4][32][34];    // 17.4 KB, partial O^T [w][d][q]
    __shared__ float lS[4][32];
    const int t = threadIdx.x, w = t >> 6, lane = t & 63;
    const int l15 = lane & 15, quad = lane >> 4;
    const int qc = blockIdx.x, hb = blockIdx.y;    // h=hb&7, b=hb>>3
    const int q0 = qc * 32;
    const int b = hb >> 3, h = hb & 7;
    const f16* Qh = Qz + (size_t)hb * NG * 512;    // 512 f16 per group chunk
    const f16* Kh = Kz + (size_t)hb * NG * 512;
    const f16* Vh = Vz + (size_t)hb * NG * 512;    // 2 half-chunks of 256 f16/group
    const int* mrow = mask + b * Ln;
    const int k_base = w * (Ln / 4);

    h8 qf[2];                                   // coalesced 1024B chunk loads
    #pragma unroll
    for (int qg = 0; qg < 2; ++qg)
        qf[qg] = *(const h8*)(Qh + ((size_t)(qc * 2 + qg) * 64 + lane) * 8);

    f4 o[2][2];                                 // [d-group][q-group]
    #pragma unroll
    for (int i = 0; i < 2; ++i)
        #pragma unroll
        for (int j = 0; j < 2; ++j) o[i][j] = (f4){0.f, 0.f, 0.f, 0.f};
    float l_run[2] = {0.f, 0.f};                // per-lane q = q0 + qg*16 + l15

    for (int kt = 0; kt < Ln / 4 / 64; ++kt) {
        const int k0 = k_base + kt * 64;
        #pragma unroll
        for (int tt = 0; tt < 4; ++tt) {
            const int g = (k0 >> 4) + tt;
            // coalesced: kf 1024B, va 512B each, mask 64B
            h8 kf = *(const h8*)(Kh + ((size_t)g * 64 + lane) * 8);
            const int4 mk = *(const int4*)(mrow + g * 16 + quad * 4);
            f4 bias4 = { mk.x ? 0.f : NEGC, mk.y ? 0.f : NEGC,
                         mk.z ? 0.f : NEGC, mk.w ? 0.f : NEGC };
            h4 va0 = *(const h4*)(Vh + ((size_t)(g * 2)     * 64 + lane) * 4);
            h4 va1 = *(const h4*)(Vh + ((size_t)(g * 2 + 1) * 64 + lane) * 4);
            f4 s[2];
            #pragma unroll
            for (int qg = 0; qg < 2; ++qg)
                s[qg] = __builtin_amdgcn_mfma_f32_16x16x32_f16(kf, qf[qg], bias4, 0, 0, 0);
            #pragma unroll
            for (int qg = 0; qg < 2; ++qg) {
                h4 pf;
                #pragma unroll
                for (int r = 0; r < 4; ++r) {
                    const float pv = __expf(s[qg][r]);
                    l_run[qg] += pv;
                    pf[r] = (f16)pv;
                }
                o[0][qg] = __builtin_amdgcn_mfma_f32_16x16x16f16(va0, pf, o[0][qg], 0, 0, 0);
                o[1][qg] = __builtin_amdgcn_mfma_f32_16x16x16f16(va1, pf, o[1][qg], 0, 0, 0);
            }
        }
    }
    // ---- wave partials ----
    #pragma unroll
    for (int qg = 0; qg < 2; ++qg) {
        l_run[qg] += __shfl_xor(l_run[qg], 16, 64);
        l_run[qg] += __shfl_xor(l_run[qg], 32, 64);
        if (quad == 0) lS[w][qg * 16 + l15] = l_run[qg];
        #pragma unroll
        for (int dg = 0; dg < 2; ++dg)
            #pragma unroll
            for (int r = 0; r < 4; ++r)
                Os[w][dg * 16 + quad * 4 + r][qg * 16 + l15] = o[dg][qg][r];
    }
    __syncthreads();

    // ---- combine 4 chunks -> Oz chunk (gm = global row>>4, h) ----
    if (t < 128) {
        const int cq = t & 31, dv = t >> 5;      // dv = depth quad 0..3
        const float ls = lS[0][cq] + lS[1][cq] + lS[2][cq] + lS[3][cq];
        const float inv = 1.0f / ls;
        h8 pack;
        #pragma unroll
        for (int i = 0; i < 8; ++i) {
            const int dd = dv * 8 + i;
            const float ov = Os[0][dd][cq] + Os[1][dd][cq] +
                             Os[2][dd][cq] + Os[3][dd][cq];
            pack[i] = (f16)(ov * inv);
        }
        const int gm = b * NG + ((q0 + cq) >> 4);      // global-row group
        *(h8*)(Oz + (((size_t)gm * 8 + h) * 64 + dv * 16 + (cq & 15)) * 8) = pack;
    }
}

// ---- Kernel 3: out projection, no LDS, no barriers. Block g = 16 rows. ----
__global__ __launch_bounds__(256) void out_gemm(
    const f16* __restrict__ Oz, const float* __restrict__ Wo,
    const float* __restrict__ bo, float* __restrict__ out)
{
    const int t = threadIdx.x, w = t >> 6, lane = t & 63;
    const int l15 = lane & 15, quad = lane >> 4;
    const int g = blockIdx.x;                // 16-row group

    h8 af[8];                                // A-frags: own Oz rows, coalesced
    #pragma unroll
    for (int h = 0; h < 8; ++h)
        af[h] = *(const h8*)(Oz + (((size_t)g * 8 + h) * 64 + lane) * 8);

    const float* Wop = Wo + w * 64 + l15;    // this wave's 64-col slice
    f4 acc[4] = {{0.f,0.f,0.f,0.f},{0.f,0.f,0.f,0.f},
                 {0.f,0.f,0.f,0.f},{0.f,0.f,0.f,0.f}};
    #pragma unroll
    for (int h = 0; h < 8; ++h) {
        h8 bf[4];
        #pragma unroll
        for (int tt = 0; tt < 4; ++tt)
            #pragma unroll
            for (int j = 0; j < 8; ++j)
                bf[tt][j] = (f16)Wop[(size_t)(h * 32 + quad * 8 + j) * DIN + tt * 16];
        #pragma unroll
        for (int tt = 0; tt < 4; ++tt)
            acc[tt] = __builtin_amdgcn_mfma_f32_16x16x32_f16(af[h], bf[tt], acc[tt], 0, 0, 0);
    }
    #pragma unroll
    for (int tt = 0; tt < 4; ++tt) {
        const int c = w * 64 + tt * 16 + l15;
        const float bb = bo[c];
        #pragma unroll
        for (int r = 0; r < 4; ++r)
            out[(size_t)(g * 16 + quad * 4 + r) * DIN + c] = acc[tt][r] + bb;
    }
}

// ===========================================================================
// FALLBACK (ws < 8 MB): proven R4 zero-workspace self-aliasing 5-launch path.
// ===========================================================================
__global__ __launch_bounds__(256) void fb_projKV(
    const float* __restrict__ Xk, const float* __restrict__ Xv,
    const float* __restrict__ Wk, const float* __restrict__ Wv,
    const float* __restrict__ bk, const float* __restrict__ bv,
    f16* S, int b)
{
    __shared__ f16 Wl[64 * WLS];
    const int p = blockIdx.z;
    const float* X = (p ? Xv : Xk) + (size_t)b * Ln * DIN;
    const float* W = p ? Wv : Wk;
    const float* bias = p ? bv : bk;

    const int t = threadIdx.x, w = t >> 6, lane = t & 63;
    const int l15 = lane & 15, quad = lane >> 4;
    const int n0 = blockIdx.y * 64;

    {
        const int nl = t & 63, kb = t >> 6;
        for (int kk = 0; kk < 64; ++kk) {
            const int k = kk * 4 + kb;
            Wl[nl * WLS + k] = (f16)W[(size_t)k * DIN + n0 + nl];
        }
    }
    __syncthreads();

    const int m0w = blockIdx.x * 128 + w * 32;
    const float* A0 = X + (size_t)(m0w + l15) * DIN;
    const float* A1 = X + (size_t)(m0w + 16 + l15) * DIN;

    f4 acc[2][4];
    #pragma unroll
    for (int mi = 0; mi < 2; ++mi)
        #pragma unroll
        for (int tt = 0; tt < 4; ++tt) acc[mi][tt] = (f4){0.f, 0.f, 0.f, 0.f};

    for (int k0 = 0; k0 < DIN; k0 += 32) {
        float4 xa0 = *(const float4*)(A0 + k0 + quad * 8);
        float4 xb0 = *(const float4*)(A0 + k0 + quad * 8 + 4);
        float4 xa1 = *(const float4*)(A1 + k0 + quad * 8);
        float4 xb1 = *(const float4*)(A1 + k0 + quad * 8 + 4);
        h8 af0 = { (f16)xa0.x, (f16)xa0.y, (f16)xa0.z, (f16)xa0.w,
                   (f16)xb0.x, (f16)xb0.y, (f16)xb0.z, (f16)xb0.w };
        h8 af1 = { (f16)xa1.x, (f16)xa1.y, (f16)xa1.z, (f16)xa1.w,
                   (f16)xb1.x, (f16)xb1.y, (f16)xb1.z, (f16)xb1.w };
        #pragma unroll
        for (int tt = 0; tt < 4; ++tt) {
            h8 bf = *(const h8*)(Wl + (tt * 16 + l15) * WLS + k0 + quad * 8);
            acc[0][tt] = __builtin_amdgcn_mfma_f32_16x16x32_f16(af0, bf, acc[0][tt], 0, 0, 0);
            acc[1][tt] = __builtin_amdgcn_mfma_f32_16x16x32_f16(af1, bf, acc[1][tt], 0, 0, 0);
        }
    }
    #pragma unroll
    for (int mi = 0; mi < 2; ++mi)
        #pragma unroll
        for (int tt = 0; tt < 4; ++tt) {
            const int c = n0 + tt * 16 + l15;
            const float bb = bias[c];
            const int h = c >> 5, dd = c & 31;
            #pragma unroll
            for (int r = 0; r < 4; ++r) {
                const int l = m0w + mi * 16 + quad * 4 + r;
                const float v = acc[mi][tt][r] + bb;
                const unsigned hg = (unsigned)h * 128 + (l >> 4);
                unsigned j;
                if (!p)
                    j = (hg * 64 + (unsigned)(dd >> 3) * 16 + (l & 15)) * 8 + (dd & 7);
                else
                    j = 524288u + ((hg * 2 + (dd >> 4)) * 64
                        + (unsigned)((l & 15) >> 2) * 16 + (dd & 15)) * 4 + (l & 3);
                S[(((size_t)(j >> 12)) << 13) + 4096u + (j & 4095u)] = (f16)v;
            }
        }
}

__global__ __launch_bounds__(512) void fb_flashQ(
    const float* __restrict__ Xq, const float* __restrict__ Wq,
    const float* __restrict__ bq, const int* __restrict__ mask,
    float* outbuf, int b)
{
    __shared__ union {
        struct { f16 Wlq[32 * WLS]; f16 Qs[2048]; } a;
        struct { float Os[8][32][68]; float lS[8][64]; } c;
    } sm;
    f16* S = (f16*)outbuf;
    const int t = threadIdx.x, w = t >> 6, lane = t & 63;
    const int l15 = lane & 15, quad = lane >> 4;
    const int h = blockIdx.x, q0 = blockIdx.y * 64;

    {
        const int nl = t & 31, kb = t >> 5;
        for (int kk = 0; kk < 16; ++kk) {
            const int k = kk * 16 + kb;
            sm.a.Wlq[nl * WLS + k] = (f16)Wq[(size_t)k * DIN + h * 32 + nl];
        }
    }
    __syncthreads();

    if (w < 4) {
        const float* A0 = Xq + (size_t)(b * Ln + q0 + w * 16 + l15) * DIN;
        f4 a2[2] = { {0.f,0.f,0.f,0.f}, {0.f,0.f,0.f,0.f} };
        #pragma unroll
        for (int kk = 0; kk < 8; ++kk) {
            const int k0 = kk * 32;
            float4 xa = *(const float4*)(A0 + k0 + quad * 8);
            float4 xb = *(const float4*)(A0 + k0 + quad * 8 + 4);
            h8 af = { (f16)xa.x, (f16)xa.y, (f16)xa.z, (f16)xa.w,
                      (f16)xb.x, (f16)xb.y, (f16)xb.z, (f16)xb.w };
            #pragma unroll
            for (int tt = 0; tt < 2; ++tt) {
                h8 bf = *(const h8*)(sm.a.Wlq + (tt * 16 + l15) * WLS + k0 + quad * 8);
                a2[tt] = __builtin_amdgcn_mfma_f32_16x16x32_f16(af, bf, a2[tt], 0, 0, 0);
            }
        }
        #pragma unroll
        for (int tt = 0; tt < 2; ++tt) {
            const int c = tt * 16 + l15;
            const float bb = bq[h * 32 + c];
            #pragma unroll
            for (int r = 0; r < 4; ++r) {
                const int lc = quad * 4 + r;
                sm.a.Qs[((size_t)w * 64 + (c >> 3) * 16 + lc) * 8 + (c & 7)] =
                    (f16)((a2[tt][r] + bb) * SCALE);
            }
        }
    }
    __syncthreads();
    h8 qf[4];
    #pragma unroll
    for (int qg = 0; qg < 4; ++qg)
        qf[qg] = *(const h8*)(sm.a.Qs + ((size_t)qg * 64 + lane) * 8);
    __syncthreads();

    const int* mrow = mask + b * Ln;
    f4 o[2][4];
    #pragma unroll
    for (int i = 0; i < 2; ++i)
        #pragma unroll
        for (int j = 0; j < 4; ++j) o[i][j] = (f4){0.f, 0.f, 0.f, 0.f};
    float l_run[4] = {0.f, 0.f, 0.f, 0.f};
    const int k_base = w * (Ln / 8);

    for (int kt = 0; kt < Ln / 8 / 64; ++kt) {
        const int k0 = k_base + kt * 64;
        #pragma unroll
        for (int tt = 0; tt < 4; ++tt) {
            const int g = (k0 >> 4) + tt;
            const size_t kaddr = ((size_t)(h * 16 + (g >> 3)) << 13) + 4096u
                               + (size_t)((g & 7) * 512 + lane * 8);
            h8 kf = *(const h8*)(S + kaddr);
            const int4 mk = *(const int4*)(mrow + g * 16 + quad * 4);
            f4 bias4 = { mk.x ? 0.f : NEGC, mk.y ? 0.f : NEGC,
                         mk.z ? 0.f : NEGC, mk.w ? 0.f : NEGC };
            const size_t vaddr = ((size_t)(128 + h * 16 + (g >> 3)) << 13) + 4096u
                               + (size_t)((g & 7) * 512 + lane * 4);
            h4 va0 = *(const h4*)(S + vaddr);
            h4 va1 = *(const h4*)(S + vaddr + 256);
            f4 s_[4];
            #pragma unroll
            for (int qg = 0; qg < 4; ++qg)
                s_[qg] = __builtin_amdgcn_mfma_f32_16x16x32_f16(kf, qf[qg], bias4, 0, 0, 0);
            #pragma unroll
            for (int qg = 0; qg < 4; ++qg) {
                h4 pf;
                #pragma unroll
                for (int r = 0; r < 4; ++r) {
                    const float pv = __expf(s_[qg][r]);
                    l_run[qg] += pv;
                    pf[r] = (f16)pv;
                }
                o[0][qg] = __builtin_amdgcn_mfma_f32_16x16x16f16(va0, pf, o[0][qg], 0, 0, 0);
                o[1][qg] = __builtin_amdgcn_mfma_f32_16x16x16f16(va1, pf, o[1][qg], 0, 0, 0);
            }
        }
    }
    #pragma unroll
    for (int qg = 0; qg < 4; ++qg) {
        l_run[qg] += __shfl_xor(l_run[qg], 16, 64);
        l_run[qg] += __shfl_xor(l_run[qg], 32, 64);
        if (quad == 0) sm.c.lS[w][qg * 16 + l15] = l_run[qg];
        #pragma unroll
        for (int dg = 0; dg < 2; ++dg)
            #pragma unroll
            for (int r = 0; r < 4; ++r)
                sm.c.Os[w][dg * 16 + quad * 4 + r][qg * 16 + l15] = o[dg][qg][r];
    }
    __syncthreads();

    if (t < 256) {
        const int cq = t & 63, dv = t >> 6;
        float ls = 0.f;
        #pragma unroll
        for (int i = 0; i < 8; ++i) ls += sm.c.lS[i][cq];
        const float inv = 1.0f / ls;
        h8 pack;
        #pragma unroll
        for (int i = 0; i < 8; ++i) {
            const int dd = dv * 8 + i;
            float ov = 0.f;
            #pragma unroll
            for (int s = 0; s < 8; ++s) ov += sm.c.Os[s][dd][cq];
            pack[i] = (f16)(ov * inv);
        }
        const int gm = b * 128 + ((q0 + cq) >> 4);
        *(h8*)(S + (size_t)gm * 8192
               + (size_t)(h * 64 + dv * 16 + (cq & 15)) * 8) = pack;
    }
}

__global__ __launch_bounds__(256) void fb_outproj(
    const float* __restrict__ Wo, const float* __restrict__ bo, float* outbuf)
{
    f16* S = (f16*)outbuf;
    const int t = threadIdx.x, w = t >> 6, lane = t & 63;
    const int l15 = lane & 15, quad = lane >> 4;
    const int g = blockIdx.x;

    h8 af[8];
    #pragma unroll
    for (int h = 0; h < 8; ++h)
        af[h] = *(const h8*)(S + (size_t)g * 8192 + (size_t)(h * 64 + lane) * 8);
    __syncthreads();

    const float* Wop = Wo + w * 64 + l15;
    f4 acc[4] = {{0.f,0.f,0.f,0.f},{0.f,0.f,0.f,0.f},
                 {0.f,0.f,0.f,0.f},{0.f,0.f,0.f,0.f}};
    #pragma unroll
    for (int h = 0; h < 8; ++h) {
        h8 bf[4];
        #pragma unroll
        for (int tt = 0; tt < 4; ++tt)
            #pragma unroll
            for (int j = 0; j < 8; ++j)
                bf[tt][j] = (f16)Wop[(size_t)(h * 32 + quad * 8 + j) * DIN + tt * 16];
        #pragma unroll
        for (int tt = 0; tt < 4; ++tt)
            acc[tt] = __builtin_amdgcn_mfma_f32_16x16x32_f16(af[h], bf[tt], acc[tt], 0, 0, 0);
    }
    #pragma unroll
    for (int tt = 0; tt < 4; ++tt) {
        const int c = w * 64 + tt * 16 + l15;
        const float bb = bo[c];
        #pragma unroll
        for (int r = 0; r < 4; ++r)
            outbuf[(size_t)(g * 16 + quad * 4 + r) * DIN + c] = acc[tt][r] + bb;
    }
}

// ===========================================================================
extern "C" void kernel_launch(void* const* d_in, const int* in_sizes, int n_in,
                              void* d_out, int out_size, void* d_ws, size_t ws_size,
                              hipStream_t stream) {
    (void)in_sizes; (void)n_in; (void)out_size;
    const float* Xq = (const float*)d_in[0];
    const float* Xk = (const float*)d_in[1];
    const float* Xv = (const float*)d_in[2];
    const int*  mask = (const int*)d_in[3];
    const float* Wq = (const float*)d_in[4];
    const float* bq = (const float*)d_in[5];
    const float* Wk = (const float*)d_in[6];
    const float* bk = (const float*)d_in[7];
    const float* Wv = (const float*)d_in[8];
    const float* bv = (const float*)d_in[9];
    const float* Wo = (const float*)d_in[10];
    const float* bo = (const float*)d_in[11];
    float* out = (float*)d_out;

    const size_t HB_E = (size_t)Bn * Hn * Ln * DEPTH;     // 1M f16 each
    const size_t need = 4 * HB_E * sizeof(f16);           // 8 MB

    if (ws_size >= need) {
        // Main path: ws poison is unconditional -> using ws is free.
        f16* Qz = (f16*)d_ws;
        f16* Kz = Qz + HB_E;
        f16* Vz = Kz + HB_E;
        f16* Oz = Vz + HB_E;
        proj_gemm<<<dim3(Bn * Ln / 128, DIN / 64, 3), 256, 0, stream>>>(
            Xq, Xk, Xv, Wq, Wk, Wv, bq, bk, bv, Qz, Kz, Vz);
        flash_mfma<<<dim3(Ln / 32, Bn * Hn), 256, 0, stream>>>(Qz, Kz, Vz, mask, Oz);
        out_gemm<<<Bn * Ln / 16, 256, 0, stream>>>(Oz, Wo, bo, out);
    } else {
        // Proven R4 zero-workspace self-aliasing path.
        f16* S = (f16*)out;
        fb_projKV<<<dim3(16, 4, 2), 256, 0, stream>>>(Xk, Xv, Wk, Wv, bk, bv, S, 0);
        fb_flashQ<<<dim3(8, 32), 512, 0, stream>>>(Xq, Wq, bq, mask, out, 0);
        fb_projKV<<<dim3(16, 4, 2), 256, 0, stream>>>(Xk, Xv, Wk, Wv, bk, bv, S, 1);
        fb_flashQ<<<dim3(8, 32), 512, 0, stream>>>(Xq, Wq, bq, mask, out, 1);
        fb_outproj<<<256, 256, 0, stream>>>(Wo, bo, out);
    }
}

// Round 6
// 121.226 us; speedup vs baseline: 2.9808x; 1.0098x over previous
//
#include <hip/hip_runtime.h>

#define Bn 2
#define Ln 2048
#define DIN 256
#define Hn 8
#define DEPTH 32
#define SCALE 0.17677669529663687f      // 1/sqrt(32)
#define NEGC (-4294967296.0f)           // float32(-2^32+1)
#define NG  (Ln / 16)                   // 128 16-row groups per (b,h)
#define WLS 264                         // LDS W^T row stride (f16) [fallback]

typedef _Float16 f16;
typedef _Float16 h8 __attribute__((ext_vector_type(8)));   // K=32 A/B frag
typedef _Float16 h4 __attribute__((ext_vector_type(4)));   // K=16 A/B frag
typedef float f4 __attribute__((ext_vector_type(4)));      // C/D frag

// ===========================================================================
// MAIN PATH (ws >= 8 MB; the 268 MB ws poison-fill is an UNCONDITIONAL ~44us
// harness tax -> ws is free; minimize kernel latency, not ws usage).
//   L1 proj_gemm (768 blk, no-LDS): QKV -> Qz (pre-scaled), Kz, Vz in ws
//   L2 flash_mfma (1024 blk x 512 thr, 8-way split-K, XCD-swizzled) -> Oz
//   L3 out_gemm  (512 blk, no-LDS): out-projection -> out
// All three use the proven "no barrier-separated staging" structure: every
// global load is independent and fully pipelined (R3->R4 lesson: LDS-staged
// rounds cost 10x vs direct pipelined scalar loads).
// Frag-swizzled ws layouts (proven):
//   Qz/Kz chunk per (hb, 16-row group g) = 512 f16: lane(quad*16+l15) holds
//     8 f16 = row (g*16+l15), depth (quad*8..+7).
//   Vz per (hb,g): 2 half-chunks of 256 f16 (d-halves); lane holds 4 f16 =
//     V[key=g*16+quad*4+j][d=dhalf*16+l15].
//   Oz chunk per (row-group gm, h) = 512 f16: lane holds O[row=gm*16+l15]
//     [d=quad*8..+7].
// ===========================================================================

// ---- Kernel 1: QKV projection, no LDS. Wave = 16m x 64n tile. -------------
__global__ __launch_bounds__(256) void proj_gemm(
    const float* __restrict__ Xq, const float* __restrict__ Xk, const float* __restrict__ Xv,
    const float* __restrict__ Wq, const float* __restrict__ Wk, const float* __restrict__ Wv,
    const float* __restrict__ bq, const float* __restrict__ bk, const float* __restrict__ bv,
    f16* __restrict__ Qz, f16* __restrict__ Kz, f16* __restrict__ Vz)
{
    const int p = blockIdx.z;
    const float* X = p == 0 ? Xq : p == 1 ? Xk : Xv;
    const float* W = p == 0 ? Wq : p == 1 ? Wk : Wv;
    const float* bias = p == 0 ? bq : p == 1 ? bk : bv;

    const int t = threadIdx.x, w = t >> 6, lane = t & 63;
    const int l15 = lane & 15, quad = lane >> 4;
    const int n0 = blockIdx.y * 64;
    const int m0 = blockIdx.x * 64 + w * 16;

    const float* A0 = X + (size_t)(m0 + l15) * DIN;
    const float* Wp = W + n0 + l15;          // this lane's n-column base

    f4 acc[4] = {{0.f,0.f,0.f,0.f},{0.f,0.f,0.f,0.f},
                 {0.f,0.f,0.f,0.f},{0.f,0.f,0.f,0.f}};
    #pragma unroll
    for (int kk = 0; kk < 8; ++kk) {
        const int k0 = kk * 32;
        float4 xa = *(const float4*)(A0 + k0 + quad * 8);
        float4 xb = *(const float4*)(A0 + k0 + quad * 8 + 4);
        h8 af = { (f16)xa.x, (f16)xa.y, (f16)xa.z, (f16)xa.w,
                  (f16)xb.x, (f16)xb.y, (f16)xb.z, (f16)xb.w };
        h8 bf[4];
        #pragma unroll
        for (int tt = 0; tt < 4; ++tt)
            #pragma unroll
            for (int j = 0; j < 8; ++j)
                bf[tt][j] = (f16)Wp[(size_t)(k0 + quad * 8 + j) * DIN + tt * 16];
        #pragma unroll
        for (int tt = 0; tt < 4; ++tt)
            acc[tt] = __builtin_amdgcn_mfma_f32_16x16x32_f16(af, bf[tt], acc[tt], 0, 0, 0);
    }
    #pragma unroll
    for (int tt = 0; tt < 4; ++tt) {
        const int c = n0 + tt * 16 + l15;        // 16-tile never straddles a head
        const float bb = bias[c];
        const int h = c >> 5, dd = c & 31;
        #pragma unroll
        for (int r = 0; r < 4; ++r) {
            const int row = m0 + quad * 4 + r;
            const int b = row >> 11, l = row & (Ln - 1);
            const float v = acc[tt][r] + bb;
            const size_t hbg = (size_t)(b * Hn + h) * NG + (l >> 4);
            if (p == 0)        // Q swizzled (K=32 B-frag chunks), pre-scaled
                Qz[(hbg * 64 + (dd >> 3) * 16 + (l & 15)) * 8 + (dd & 7)] =
                    (f16)(v * SCALE);
            else if (p == 1)   // K swizzled (K=32 A-frag chunks)
                Kz[(hbg * 64 + (dd >> 3) * 16 + (l & 15)) * 8 + (dd & 7)] = (f16)v;
            else               // V swizzled (K=16 A-frag chunks, 2 d-halves)
                Vz[((hbg * 2 + (dd >> 4)) * 64 + ((l & 15) >> 2) * 16 + (dd & 15)) * 4
                   + (l & 3)] = (f16)v;
        }
    }
}

// ---- Kernel 2: 8-way split-K MFMA flash, 32 q-rows/block, XCD-swizzled. ---
// 1D grid 1024: swz = (bid&7)*128 + bid>>3 (bijective); hb = swz>>6, qc = swz&63.
// Wave w covers keys [w*256, (w+1)*256) = 16 groups (half the R5 chain).
__global__ __launch_bounds__(512) void flash_mfma(
    const f16* __restrict__ Qz, const f16* __restrict__ Kz,
    const f16* __restrict__ Vz, const int* __restrict__ mask,
    f16* __restrict__ Oz)
{
    __shared__ float Os[8][32][34];    // 34.8 KB, partial O^T [w][d][q]
    __shared__ float lS[8][32];
    const int t = threadIdx.x, w = t >> 6, lane = t & 63;
    const int l15 = lane & 15, quad = lane >> 4;
    const int bid = blockIdx.x;
    const int swz = (bid & 7) * 128 + (bid >> 3);
    const int hb = swz >> 6, qc = swz & 63;        // h=hb&7, b=hb>>3
    const int q0 = qc * 32;
    const int b = hb >> 3, h = hb & 7;
    const f16* Qh = Qz + (size_t)hb * NG * 512;    // 512 f16 per group chunk
    const f16* Kh = Kz + (size_t)hb * NG * 512;
    const f16* Vh = Vz + (size_t)hb * NG * 512;    // 2 half-chunks of 256 f16/group
    const int* mrow = mask + b * Ln;
    const int k_base = w * (Ln / 8);

    h8 qf[2];                                   // coalesced 1024B chunk loads
    #pragma unroll
    for (int qg = 0; qg < 2; ++qg)
        qf[qg] = *(const h8*)(Qh + ((size_t)(qc * 2 + qg) * 64 + lane) * 8);

    f4 o[2][2];                                 // [d-group][q-group]
    #pragma unroll
    for (int i = 0; i < 2; ++i)
        #pragma unroll
        for (int j = 0; j < 2; ++j) o[i][j] = (f4){0.f, 0.f, 0.f, 0.f};
    float l_run[2] = {0.f, 0.f};                // per-lane q = q0 + qg*16 + l15

    for (int kt = 0; kt < Ln / 8 / 64; ++kt) {  // 4 iters x 4 groups
        const int k0 = k_base + kt * 64;
        #pragma unroll
        for (int tt = 0; tt < 4; ++tt) {
            const int g = (k0 >> 4) + tt;
            // coalesced: kf 1024B, va 512B each, mask 64B
            h8 kf = *(const h8*)(Kh + ((size_t)g * 64 + lane) * 8);
            const int4 mk = *(const int4*)(mrow + g * 16 + quad * 4);
            f4 bias4 = { mk.x ? 0.f : NEGC, mk.y ? 0.f : NEGC,
                         mk.z ? 0.f : NEGC, mk.w ? 0.f : NEGC };
            h4 va0 = *(const h4*)(Vh + ((size_t)(g * 2)     * 64 + lane) * 4);
            h4 va1 = *(const h4*)(Vh + ((size_t)(g * 2 + 1) * 64 + lane) * 4);
            f4 s[2];
            #pragma unroll
            for (int qg = 0; qg < 2; ++qg)
                s[qg] = __builtin_amdgcn_mfma_f32_16x16x32_f16(kf, qf[qg], bias4, 0, 0, 0);
            #pragma unroll
            for (int qg = 0; qg < 2; ++qg) {
                h4 pf;
                #pragma unroll
                for (int r = 0; r < 4; ++r) {
                    const float pv = __expf(s[qg][r]);
                    l_run[qg] += pv;
                    pf[r] = (f16)pv;
                }
                o[0][qg] = __builtin_amdgcn_mfma_f32_16x16x16f16(va0, pf, o[0][qg], 0, 0, 0);
                o[1][qg] = __builtin_amdgcn_mfma_f32_16x16x16f16(va1, pf, o[1][qg], 0, 0, 0);
            }
        }
    }
    // ---- wave partials ----
    #pragma unroll
    for (int qg = 0; qg < 2; ++qg) {
        l_run[qg] += __shfl_xor(l_run[qg], 16, 64);
        l_run[qg] += __shfl_xor(l_run[qg], 32, 64);
        if (quad == 0) lS[w][qg * 16 + l15] = l_run[qg];
        #pragma unroll
        for (int dg = 0; dg < 2; ++dg)
            #pragma unroll
            for (int r = 0; r < 4; ++r)
                Os[w][dg * 16 + quad * 4 + r][qg * 16 + l15] = o[dg][qg][r];
    }
    __syncthreads();

    // ---- combine 8 chunks -> Oz chunk (gm = global row>>4, h) ----
    if (t < 128) {
        const int cq = t & 31, dv = t >> 5;      // dv = depth quad 0..3
        float ls = 0.f;
        #pragma unroll
        for (int i = 0; i < 8; ++i) ls += lS[i][cq];
        const float inv = 1.0f / ls;
        h8 pack;
        #pragma unroll
        for (int i = 0; i < 8; ++i) {
            const int dd = dv * 8 + i;
            float ov = 0.f;
            #pragma unroll
            for (int s = 0; s < 8; ++s) ov += Os[s][dd][cq];
            pack[i] = (f16)(ov * inv);
        }
        const int gm = b * NG + ((q0 + cq) >> 4);      // global-row group
        *(h8*)(Oz + (((size_t)gm * 8 + h) * 64 + dv * 16 + (cq & 15)) * 8) = pack;
    }
}

// ---- Kernel 3: out projection, no LDS/barriers. Block = 16 rows x 128 cols.
__global__ __launch_bounds__(256) void out_gemm(
    const f16* __restrict__ Oz, const float* __restrict__ Wo,
    const float* __restrict__ bo, float* __restrict__ out)
{
    const int t = threadIdx.x, w = t >> 6, lane = t & 63;
    const int l15 = lane & 15, quad = lane >> 4;
    const int g = blockIdx.x >> 1, nh = blockIdx.x & 1;   // 16-row group, n-half

    h8 af[8];                                // A-frags: own Oz rows, coalesced
    #pragma unroll
    for (int h = 0; h < 8; ++h)
        af[h] = *(const h8*)(Oz + (((size_t)g * 8 + h) * 64 + lane) * 8);

    const float* Wop = Wo + nh * 128 + w * 32 + l15;   // this wave's 32-col slice
    f4 acc[2] = {{0.f,0.f,0.f,0.f},{0.f,0.f,0.f,0.f}};
    #pragma unroll
    for (int h = 0; h < 8; ++h) {
        h8 bf[2];
        #pragma unroll
        for (int tt = 0; tt < 2; ++tt)
            #pragma unroll
            for (int j = 0; j < 8; ++j)
                bf[tt][j] = (f16)Wop[(size_t)(h * 32 + quad * 8 + j) * DIN + tt * 16];
        #pragma unroll
        for (int tt = 0; tt < 2; ++tt)
            acc[tt] = __builtin_amdgcn_mfma_f32_16x16x32_f16(af[h], bf[tt], acc[tt], 0, 0, 0);
    }
    #pragma unroll
    for (int tt = 0; tt < 2; ++tt) {
        const int c = nh * 128 + w * 32 + tt * 16 + l15;
        const float bb = bo[c];
        #pragma unroll
        for (int r = 0; r < 4; ++r)
            out[(size_t)(g * 16 + quad * 4 + r) * DIN + c] = acc[tt][r] + bb;
    }
}

// ===========================================================================
// FALLBACK (ws < 8 MB): proven R4 zero-workspace self-aliasing 5-launch path.
// ===========================================================================
__global__ __launch_bounds__(256) void fb_projKV(
    const float* __restrict__ Xk, const float* __restrict__ Xv,
    const float* __restrict__ Wk, const float* __restrict__ Wv,
    const float* __restrict__ bk, const float* __restrict__ bv,
    f16* S, int b)
{
    __shared__ f16 Wl[64 * WLS];
    const int p = blockIdx.z;
    const float* X = (p ? Xv : Xk) + (size_t)b * Ln * DIN;
    const float* W = p ? Wv : Wk;
    const float* bias = p ? bv : bk;

    const int t = threadIdx.x, w = t >> 6, lane = t & 63;
    const int l15 = lane & 15, quad = lane >> 4;
    const int n0 = blockIdx.y * 64;

    {
        const int nl = t & 63, kb = t >> 6;
        for (int kk = 0; kk < 64; ++kk) {
            const int k = kk * 4 + kb;
            Wl[nl * WLS + k] = (f16)W[(size_t)k * DIN + n0 + nl];
        }
    }
    __syncthreads();

    const int m0w = blockIdx.x * 128 + w * 32;
    const float* A0 = X + (size_t)(m0w + l15) * DIN;
    const float* A1 = X + (size_t)(m0w + 16 + l15) * DIN;

    f4 acc[2][4];
    #pragma unroll
    for (int mi = 0; mi < 2; ++mi)
        #pragma unroll
        for (int tt = 0; tt < 4; ++tt) acc[mi][tt] = (f4){0.f, 0.f, 0.f, 0.f};

    for (int k0 = 0; k0 < DIN; k0 += 32) {
        float4 xa0 = *(const float4*)(A0 + k0 + quad * 8);
        float4 xb0 = *(const float4*)(A0 + k0 + quad * 8 + 4);
        float4 xa1 = *(const float4*)(A1 + k0 + quad * 8);
        float4 xb1 = *(const float4*)(A1 + k0 + quad * 8 + 4);
        h8 af0 = { (f16)xa0.x, (f16)xa0.y, (f16)xa0.z, (f16)xa0.w,
                   (f16)xb0.x, (f16)xb0.y, (f16)xb0.z, (f16)xb0.w };
        h8 af1 = { (f16)xa1.x, (f16)xa1.y, (f16)xa1.z, (f16)xa1.w,
                   (f16)xb1.x, (f16)xb1.y, (f16)xb1.z, (f16)xb1.w };
        #pragma unroll
        for (int tt = 0; tt < 4; ++tt) {
            h8 bf = *(const h8*)(Wl + (tt * 16 + l15) * WLS + k0 + quad * 8);
            acc[0][tt] = __builtin_amdgcn_mfma_f32_16x16x32_f16(af0, bf, acc[0][tt], 0, 0, 0);
            acc[1][tt] = __builtin_amdgcn_mfma_f32_16x16x32_f16(af1, bf, acc[1][tt], 0, 0, 0);
        }
    }
    #pragma unroll
    for (int mi = 0; mi < 2; ++mi)
        #pragma unroll
        for (int tt = 0; tt < 4; ++tt) {
            const int c = n0 + tt * 16 + l15;
            const float bb = bias[c];
            const int h = c >> 5, dd = c & 31;
            #pragma unroll
            for (int r = 0; r < 4; ++r) {
                const int l = m0w + mi * 16 + quad * 4 + r;
                const float v = acc[mi][tt][r] + bb;
                const unsigned hg = (unsigned)h * 128 + (l >> 4);
                unsigned j;
                if (!p)
                    j = (hg * 64 + (unsigned)(dd >> 3) * 16 + (l & 15)) * 8 + (dd & 7);
                else
                    j = 524288u + ((hg * 2 + (dd >> 4)) * 64
                        + (unsigned)((l & 15) >> 2) * 16 + (dd & 15)) * 4 + (l & 3);
                S[(((size_t)(j >> 12)) << 13) + 4096u + (j & 4095u)] = (f16)v;
            }
        }
}

__global__ __launch_bounds__(512) void fb_flashQ(
    const float* __restrict__ Xq, const float* __restrict__ Wq,
    const float* __restrict__ bq, const int* __restrict__ mask,
    float* outbuf, int b)
{
    __shared__ union {
        struct { f16 Wlq[32 * WLS]; f16 Qs[2048]; } a;
        struct { float Os[8][32][68]; float lS[8][64]; } c;
    } sm;
    f16* S = (f16*)outbuf;
    const int t = threadIdx.x, w = t >> 6, lane = t & 63;
    const int l15 = lane & 15, quad = lane >> 4;
    const int h = blockIdx.x, q0 = blockIdx.y * 64;

    {
        const int nl = t & 31, kb = t >> 5;
        for (int kk = 0; kk < 16; ++kk) {
            const int k = kk * 16 + kb;
            sm.a.Wlq[nl * WLS + k] = (f16)Wq[(size_t)k * DIN + h * 32 + nl];
        }
    }
    __syncthreads();

    if (w < 4) {
        const float* A0 = Xq + (size_t)(b * Ln + q0 + w * 16 + l15) * DIN;
        f4 a2[2] = { {0.f,0.f,0.f,0.f}, {0.f,0.f,0.f,0.f} };
        #pragma unroll
        for (int kk = 0; kk < 8; ++kk) {
            const int k0 = kk * 32;
            float4 xa = *(const float4*)(A0 + k0 + quad * 8);
            float4 xb = *(const float4*)(A0 + k0 + quad * 8 + 4);
            h8 af = { (f16)xa.x, (f16)xa.y, (f16)xa.z, (f16)xa.w,
                      (f16)xb.x, (f16)xb.y, (f16)xb.z, (f16)xb.w };
            #pragma unroll
            for (int tt = 0; tt < 2; ++tt) {
                h8 bf = *(const h8*)(sm.a.Wlq + (tt * 16 + l15) * WLS + k0 + quad * 8);
                a2[tt] = __builtin_amdgcn_mfma_f32_16x16x32_f16(af, bf, a2[tt], 0, 0, 0);
            }
        }
        #pragma unroll
        for (int tt = 0; tt < 2; ++tt) {
            const int c = tt * 16 + l15;
            const float bb = bq[h * 32 + c];
            #pragma unroll
            for (int r = 0; r < 4; ++r) {
                const int lc = quad * 4 + r;
                sm.a.Qs[((size_t)w * 64 + (c >> 3) * 16 + lc) * 8 + (c & 7)] =
                    (f16)((a2[tt][r] + bb) * SCALE);
            }
        }
    }
    __syncthreads();
    h8 qf[4];
    #pragma unroll
    for (int qg = 0; qg < 4; ++qg)
        qf[qg] = *(const h8*)(sm.a.Qs + ((size_t)qg * 64 + lane) * 8);
    __syncthreads();

    const int* mrow = mask + b * Ln;
    f4 o[2][4];
    #pragma unroll
    for (int i = 0; i < 2; ++i)
        #pragma unroll
        for (int j = 0; j < 4; ++j) o[i][j] = (f4){0.f, 0.f, 0.f, 0.f};
    float l_run[4] = {0.f, 0.f, 0.f, 0.f};
    const int k_base = w * (Ln / 8);

    for (int kt = 0; kt < Ln / 8 / 64; ++kt) {
        const int k0 = k_base + kt * 64;
        #pragma unroll
        for (int tt = 0; tt < 4; ++tt) {
            const int g = (k0 >> 4) + tt;
            const size_t kaddr = ((size_t)(h * 16 + (g >> 3)) << 13) + 4096u
                               + (size_t)((g & 7) * 512 + lane * 8);
            h8 kf = *(const h8*)(S + kaddr);
            const int4 mk = *(const int4*)(mrow + g * 16 + quad * 4);
            f4 bias4 = { mk.x ? 0.f : NEGC, mk.y ? 0.f : NEGC,
                         mk.z ? 0.f : NEGC, mk.w ? 0.f : NEGC };
            const size_t vaddr = ((size_t)(128 + h * 16 + (g >> 3)) << 13) + 4096u
                               + (size_t)((g & 7) * 512 + lane * 4);
            h4 va0 = *(const h4*)(S + vaddr);
            h4 va1 = *(const h4*)(S + vaddr + 256);
            f4 s_[4];
            #pragma unroll
            for (int qg = 0; qg < 4; ++qg)
                s_[qg] = __builtin_amdgcn_mfma_f32_16x16x32_f16(kf, qf[qg], bias4, 0, 0, 0);
            #pragma unroll
            for (int qg = 0; qg < 4; ++qg) {
                h4 pf;
                #pragma unroll
                for (int r = 0; r < 4; ++r) {
                    const float pv = __expf(s_[qg][r]);
                    l_run[qg] += pv;
                    pf[r] = (f16)pv;
                }
                o[0][qg] = __builtin_amdgcn_mfma_f32_16x16x16f16(va0, pf, o[0][qg], 0, 0, 0);
                o[1][qg] = __builtin_amdgcn_mfma_f32_16x16x16f16(va1, pf, o[1][qg], 0, 0, 0);
            }
        }
    }
    #pragma unroll
    for (int qg = 0; qg < 4; ++qg) {
        l_run[qg] += __shfl_xor(l_run[qg], 16, 64);
        l_run[qg] += __shfl_xor(l_run[qg], 32, 64);
        if (quad == 0) sm.c.lS[w][qg * 16 + l15] = l_run[qg];
        #pragma unroll
        for (int dg = 0; dg < 2; ++dg)
            #pragma unroll
            for (int r = 0; r < 4; ++r)
                sm.c.Os[w][dg * 16 + quad * 4 + r][qg * 16 + l15] = o[dg][qg][r];
    }
    __syncthreads();

    if (t < 256) {
        const int cq = t & 63, dv = t >> 6;
        float ls = 0.f;
        #pragma unroll
        for (int i = 0; i < 8; ++i) ls += sm.c.lS[i][cq];
        const float inv = 1.0f / ls;
        h8 pack;
        #pragma unroll
        for (int i = 0; i < 8; ++i) {
            const int dd = dv * 8 + i;
            float ov = 0.f;
            #pragma unroll
            for (int s = 0; s < 8; ++s) ov += sm.c.Os[s][dd][cq];
            pack[i] = (f16)(ov * inv);
        }
        const int gm = b * 128 + ((q0 + cq) >> 4);
        *(h8*)(S + (size_t)gm * 8192
               + (size_t)(h * 64 + dv * 16 + (cq & 15)) * 8) = pack;
    }
}

__global__ __launch_bounds__(256) void fb_outproj(
    const float* __restrict__ Wo, const float* __restrict__ bo, float* outbuf)
{
    f16* S = (f16*)outbuf;
    const int t = threadIdx.x, w = t >> 6, lane = t & 63;
    const int l15 = lane & 15, quad = lane >> 4;
    const int g = blockIdx.x;

    h8 af[8];
    #pragma unroll
    for (int h = 0; h < 8; ++h)
        af[h] = *(const h8*)(S + (size_t)g * 8192 + (size_t)(h * 64 + lane) * 8);
    __syncthreads();

    const float* Wop = Wo + w * 64 + l15;
    f4 acc[4] = {{0.f,0.f,0.f,0.f},{0.f,0.f,0.f,0.f},
                 {0.f,0.f,0.f,0.f},{0.f,0.f,0.f,0.f}};
    #pragma unroll
    for (int h = 0; h < 8; ++h) {
        h8 bf[4];
        #pragma unroll
        for (int tt = 0; tt < 4; ++tt)
            #pragma unroll
            for (int j = 0; j < 8; ++j)
                bf[tt][j] = (f16)Wop[(size_t)(h * 32 + quad * 8 + j) * DIN + tt * 16];
        #pragma unroll
        for (int tt = 0; tt < 4; ++tt)
            acc[tt] = __builtin_amdgcn_mfma_f32_16x16x32_f16(af[h], bf[tt], acc[tt], 0, 0, 0);
    }
    #pragma unroll
    for (int tt = 0; tt < 4; ++tt) {
        const int c = w * 64 + tt * 16 + l15;
        const float bb = bo[c];
        #pragma unroll
        for (int r = 0; r < 4; ++r)
            outbuf[(size_t)(g * 16 + quad * 4 + r) * DIN + c] = acc[tt][r] + bb;
    }
}

// ===========================================================================
extern "C" void kernel_launch(void* const* d_in, const int* in_sizes, int n_in,
                              void* d_out, int out_size, void* d_ws, size_t ws_size,
                              hipStream_t stream) {
    (void)in_sizes; (void)n_in; (void)out_size;
    const float* Xq = (const float*)d_in[0];
    const float* Xk = (const float*)d_in[1];
    const float* Xv = (const float*)d_in[2];
    const int*  mask = (const int*)d_in[3];
    const float* Wq = (const float*)d_in[4];
    const float* bq = (const float*)d_in[5];
    const float* Wk = (const float*)d_in[6];
    const float* bk = (const float*)d_in[7];
    const float* Wv = (const float*)d_in[8];
    const float* bv = (const float*)d_in[9];
    const float* Wo = (const float*)d_in[10];
    const float* bo = (const float*)d_in[11];
    float* out = (float*)d_out;

    const size_t HB_E = (size_t)Bn * Hn * Ln * DEPTH;     // 1M f16 each
    const size_t need = 4 * HB_E * sizeof(f16);           // 8 MB

    if (ws_size >= need) {
        // Main path: ws poison is unconditional -> using ws is free.
        f16* Qz = (f16*)d_ws;
        f16* Kz = Qz + HB_E;
        f16* Vz = Kz + HB_E;
        f16* Oz = Vz + HB_E;
        proj_gemm<<<dim3(Bn * Ln / 64, DIN / 64, 3), 256, 0, stream>>>(
            Xq, Xk, Xv, Wq, Wk, Wv, bq, bk, bv, Qz, Kz, Vz);
        flash_mfma<<<Ln / 32 * Bn * Hn, 512, 0, stream>>>(Qz, Kz, Vz, mask, Oz);
        out_gemm<<<Bn * Ln / 16 * 2, 256, 0, stream>>>(Oz, Wo, bo, out);
    } else {
        // Proven R4 zero-workspace self-aliasing path.
        f16* S = (f16*)out;
        fb_projKV<<<dim3(16, 4, 2), 256, 0, stream>>>(Xk, Xv, Wk, Wv, bk, bv, S, 0);
        fb_flashQ<<<dim3(8, 32), 512, 0, stream>>>(Xq, Wq, bq, mask, out, 0);
        fb_projKV<<<dim3(16, 4, 2), 256, 0, stream>>>(Xk, Xv, Wk, Wv, bk, bv, S, 1);
        fb_flashQ<<<dim3(8, 32), 512, 0, stream>>>(Xq, Wq, bq, mask, out, 1);
        fb_outproj<<<256, 256, 0, stream>>>(Wo, bo, out);
    }
}